// Round 1
// baseline (1104.885 us; speedup 1.0000x reference)
//
#include <hip/hip_runtime.h>

#define N_NODES 50000
#define N_EDGES 800000
#define N_FEAT 128
#define N_HIDDEN 128
#define N_CLASSES 64

// ---------------------------------------------------------------------------
// deg[n] = number of in-edges at node n (float, shared by both layers)
// ---------------------------------------------------------------------------
__global__ void deg_kernel(const int* __restrict__ dst, float* __restrict__ deg) {
    int e = blockIdx.x * blockDim.x + threadIdx.x;
    if (e < N_EDGES) atomicAdd(&deg[dst[e]], 1.0f);
}

// ---------------------------------------------------------------------------
// Scatter-add: hsum[dst[e], f] += x[src[e], f].  One thread per (edge, feat).
// F=128: 256-thread block covers 2 edges; reads of x rows are 512B coalesced.
// ---------------------------------------------------------------------------
template <int F>
__global__ void scatter_kernel(const float* __restrict__ x,
                               const int* __restrict__ src,
                               const int* __restrict__ dst,
                               float* __restrict__ hsum) {
    int idx = blockIdx.x * blockDim.x + threadIdx.x;
    int e = idx / F;
    int f = idx % F;
    if (e < N_EDGES) {
        int s = src[e];
        int d = dst[e];
        atomicAdd(&hsum[d * F + f], x[s * F + f]);
    }
}

// ---------------------------------------------------------------------------
// Fused SAGE epilogue per node:
//   out[node, c] = sum_k x[node,k]*Wself[k,c] + (hsum[node,k]/max(deg,1))*Wneigh[k,c] + b[c]
// One block per node, blockDim = OUT. Row staged in LDS (full row read before
// any write -> safe to write out in place over hsum when IN==OUT).
// ---------------------------------------------------------------------------
template <int IN, int OUT, bool RELU>
__global__ void sage_out_kernel(const float* __restrict__ x,
                                const float* __restrict__ hsum,
                                const float* __restrict__ deg,
                                const float* __restrict__ Wself,
                                const float* __restrict__ Wneigh,
                                const float* __restrict__ b,
                                float* __restrict__ out) {
    __shared__ float xs[IN];
    __shared__ float ms[IN];
    const int node = blockIdx.x;
    const int c = threadIdx.x;

    const float invdeg = 1.0f / fmaxf(deg[node], 1.0f);
    for (int k = c; k < IN; k += OUT) {
        xs[k] = x[node * IN + k];
        ms[k] = hsum[node * IN + k] * invdeg;
    }
    __syncthreads();

    float acc = b[c];
#pragma unroll 8
    for (int k = 0; k < IN; ++k) {
        acc += xs[k] * Wself[k * OUT + c] + ms[k] * Wneigh[k * OUT + c];
    }
    if (RELU) acc = fmaxf(acc, 0.0f);
    out[node * OUT + c] = acc;
}

extern "C" void kernel_launch(void* const* d_in, const int* in_sizes, int n_in,
                              void* d_out, int out_size, void* d_ws, size_t ws_size,
                              hipStream_t stream) {
    const float* x       = (const float*)d_in[0];
    const float* W_self1 = (const float*)d_in[1];
    const float* W_neigh1= (const float*)d_in[2];
    const float* b1      = (const float*)d_in[3];
    const float* W_self2 = (const float*)d_in[4];
    const float* W_neigh2= (const float*)d_in[5];
    const float* b2      = (const float*)d_in[6];
    const int*   src     = (const int*)d_in[7];
    const int*   dst     = (const int*)d_in[8];
    float* out = (float*)d_out;

    // workspace layout (floats):
    //   deg  : [0, 50048)                       (aligned up)
    //   buf1 : [50048, 50048 + 6.4M)            h_sum1, then relu(h1) in place
    //   buf2 : [50048+6.4M, 50048 + 12.8M)      h_sum2
    float* deg  = (float*)d_ws;
    float* buf1 = deg + 50048;
    float* buf2 = buf1 + (size_t)N_NODES * N_HIDDEN;

    // zero the accumulators (ws is poisoned 0xAA before every call)
    hipMemsetAsync(deg, 0, 50048 * sizeof(float), stream);
    hipMemsetAsync(buf1, 0, (size_t)N_NODES * N_HIDDEN * sizeof(float), stream);
    hipMemsetAsync(buf2, 0, (size_t)N_NODES * N_HIDDEN * sizeof(float), stream);

    // degrees (shared by both layers)
    deg_kernel<<<(N_EDGES + 255) / 256, 256, 0, stream>>>(dst, deg);

    // ---- layer 1 ----
    {
        const int total = N_EDGES * N_FEAT;
        scatter_kernel<N_FEAT><<<(total + 255) / 256, 256, 0, stream>>>(x, src, dst, buf1);
        // h1 = relu(x@Ws1 + mean@Wn1 + b1), written in place over buf1
        sage_out_kernel<N_FEAT, N_HIDDEN, true>
            <<<N_NODES, N_HIDDEN, 0, stream>>>(x, buf1, deg, W_self1, W_neigh1, b1, buf1);
    }

    // ---- layer 2 ----
    {
        const int total = N_EDGES * N_HIDDEN;
        scatter_kernel<N_HIDDEN><<<(total + 255) / 256, 256, 0, stream>>>(buf1, src, dst, buf2);
        sage_out_kernel<N_HIDDEN, N_CLASSES, false>
            <<<N_NODES, N_CLASSES, 0, stream>>>(buf1, buf2, deg, W_self2, W_neigh2, b2, out);
    }
}

// Round 2
// 643.055 us; speedup vs baseline: 1.7182x; 1.7182x over previous
//
#include <hip/hip_runtime.h>

#define N_NODES 50000
#define N_EDGES 800000
#define N_FEAT 128
#define N_HIDDEN 128
#define N_CLASSES 64

#define SCAN_THREADS 1024
#define SCAN_CHUNK 49  // ceil(50000/1024)

// ---------------------------------------------------------------------------
// CSR build step 1: int in-degree histogram
// ---------------------------------------------------------------------------
__global__ void hist_kernel(const int* __restrict__ dst, int* __restrict__ degi) {
    int e = blockIdx.x * blockDim.x + threadIdx.x;
    if (e < N_EDGES) atomicAdd(&degi[dst[e]], 1);
}

// ---------------------------------------------------------------------------
// CSR build step 2: exclusive prefix sum over degi[0..N) -> offsets[0..N],
// and cursor[i] = offsets[i]. Single block (one device-wide pass, ~3 us).
// ---------------------------------------------------------------------------
__global__ void scan_kernel(const int* __restrict__ degi,
                            int* __restrict__ offsets,
                            int* __restrict__ cursor) {
    __shared__ int partial[SCAN_THREADS];
    const int t = threadIdx.x;
    const int lo = t * SCAN_CHUNK;
    const int hi = min(lo + SCAN_CHUNK, N_NODES);

    // pass 1: thread-local total
    int total = 0;
    for (int i = lo; i < hi; ++i) total += degi[i];
    partial[t] = total;
    __syncthreads();

    // Hillis-Steele inclusive scan over the 1024 partials
    for (int s = 1; s < SCAN_THREADS; s <<= 1) {
        int v = (t >= s) ? partial[t - s] : 0;
        __syncthreads();
        partial[t] += v;
        __syncthreads();
    }
    int base = (t == 0) ? 0 : partial[t - 1];

    // pass 2: re-read, emit offsets (exclusive) for i in chunk
    int run = base;
    for (int i = lo; i < hi; ++i) {
        offsets[i] = run;
        cursor[i] = run;
        run += degi[i];
    }
    if (hi == N_NODES && lo <= N_NODES) {
        // the thread owning the last element writes the sentinel
        if (hi > lo || lo == N_NODES) {
            offsets[N_NODES] = run;
        }
    }
}

// ---------------------------------------------------------------------------
// CSR build step 3: fill csr_src with source node ids grouped by dst
// ---------------------------------------------------------------------------
__global__ void fill_kernel(const int* __restrict__ src, const int* __restrict__ dst,
                            int* __restrict__ cursor, int* __restrict__ csr_src) {
    int e = blockIdx.x * blockDim.x + threadIdx.x;
    if (e < N_EDGES) {
        int pos = atomicAdd(&cursor[dst[e]], 1);
        csr_src[pos] = src[e];
    }
}

// ---------------------------------------------------------------------------
// Fused SAGE layer:
//   phase 1 (wave-per-node): ms[slot][:] = mean over in-neighbors of x[src]
//   phase 2 (thread = 4 outputs): out = xs@Wself + ms@Wneigh + b (+ReLU)
// IN=128 always. OUT=128 -> 8 nodes/block; OUT=64 -> 16 nodes/block.
// LDS rows padded +2 floats: bank-conflict-free broadcasts, 8B alignment kept.
// ---------------------------------------------------------------------------
template <int IN, int OUT, bool RELU>
__global__ __launch_bounds__(256) void sage_fused_kernel(
        const float* __restrict__ xin,
        const int* __restrict__ offsets,
        const int* __restrict__ csr_src,
        const float* __restrict__ Wself,
        const float* __restrict__ Wneigh,
        const float* __restrict__ bias,
        float* __restrict__ out) {
    constexpr int TPN = OUT / 4;        // threads per node in epilogue
    constexpr int NPB = 256 / TPN;      // nodes per block (8 or 16)
    constexpr int LDW = IN + 2;         // padded LDS row stride (floats)

    __shared__ float xs[NPB][LDW];
    __shared__ float ms[NPB][LDW];

    const int tid = threadIdx.x;
    const int nodeBase = blockIdx.x * NPB;   // grid sized so nodeBase+NPB <= N

    // ---- stage self rows (coalesced float2) ----
    {
        const int nElem2 = NPB * IN / 2;     // float2 elements
        for (int idx = tid; idx < nElem2; idx += 256) {
            int r = idx / (IN / 2);
            int c2 = idx % (IN / 2);
            float2 v = *(const float2*)&xin[(size_t)(nodeBase + r) * IN + c2 * 2];
            xs[r][c2 * 2] = v.x;
            xs[r][c2 * 2 + 1] = v.y;
        }
    }

    // ---- phase 1: aggregate neighbor means, wave per node-slot ----
    {
        const int wave = tid >> 6;
        const int lane = tid & 63;
        for (int slot = wave; slot < NPB; slot += 4) {
            const int n = nodeBase + slot;
            const int off0 = offsets[n];
            const int off1 = offsets[n + 1];
            float2 acc = make_float2(0.f, 0.f);
            int i = off0;
            for (; i + 4 <= off1; i += 4) {
                int s0 = csr_src[i], s1 = csr_src[i + 1];
                int s2 = csr_src[i + 2], s3 = csr_src[i + 3];
                float2 a0 = *(const float2*)&xin[(size_t)s0 * IN + lane * 2];
                float2 a1 = *(const float2*)&xin[(size_t)s1 * IN + lane * 2];
                float2 a2 = *(const float2*)&xin[(size_t)s2 * IN + lane * 2];
                float2 a3 = *(const float2*)&xin[(size_t)s3 * IN + lane * 2];
                acc.x += a0.x + a1.x + a2.x + a3.x;
                acc.y += a0.y + a1.y + a2.y + a3.y;
            }
            for (; i < off1; ++i) {
                int s = csr_src[i];
                float2 a = *(const float2*)&xin[(size_t)s * IN + lane * 2];
                acc.x += a.x;
                acc.y += a.y;
            }
            const float invdeg = 1.0f / fmaxf((float)(off1 - off0), 1.0f);
            ms[slot][lane * 2] = acc.x * invdeg;
            ms[slot][lane * 2 + 1] = acc.y * invdeg;
        }
    }
    __syncthreads();

    // ---- phase 2: epilogue GEMM, one thread = one node-slot x 4 outputs ----
    {
        const int slot = tid / TPN;
        const int c4 = tid % TPN;               // float4 column index
        const int node = nodeBase + slot;

        const float4* Ws4 = (const float4*)Wself;   // [IN][OUT/4]
        const float4* Wn4 = (const float4*)Wneigh;
        float4 acc = ((const float4*)bias)[c4];

#pragma unroll 4
        for (int k = 0; k < IN; ++k) {
            const float xv = xs[slot][k];
            const float mv = ms[slot][k];
            const float4 w1 = Ws4[k * TPN + c4];
            const float4 w2 = Wn4[k * TPN + c4];
            acc.x += xv * w1.x + mv * w2.x;
            acc.y += xv * w1.y + mv * w2.y;
            acc.z += xv * w1.z + mv * w2.z;
            acc.w += xv * w1.w + mv * w2.w;
        }
        if (RELU) {
            acc.x = fmaxf(acc.x, 0.f);
            acc.y = fmaxf(acc.y, 0.f);
            acc.z = fmaxf(acc.z, 0.f);
            acc.w = fmaxf(acc.w, 0.f);
        }
        ((float4*)out)[(size_t)node * TPN + c4] = acc;
    }
}

extern "C" void kernel_launch(void* const* d_in, const int* in_sizes, int n_in,
                              void* d_out, int out_size, void* d_ws, size_t ws_size,
                              hipStream_t stream) {
    const float* x        = (const float*)d_in[0];
    const float* W_self1  = (const float*)d_in[1];
    const float* W_neigh1 = (const float*)d_in[2];
    const float* b1       = (const float*)d_in[3];
    const float* W_self2  = (const float*)d_in[4];
    const float* W_neigh2 = (const float*)d_in[5];
    const float* b2       = (const float*)d_in[6];
    const int*   src      = (const int*)d_in[7];
    const int*   dst      = (const int*)d_in[8];
    float* out = (float*)d_out;

    // workspace layout (ints/floats, 4B units):
    int*   degi    = (int*)d_ws;                   // 50048
    int*   offsets = degi + 50048;                 // 50048 (uses N+1=50001)
    int*   cursor  = offsets + 50048;              // 50048
    int*   csr_src = cursor + 50048;               // 800000
    float* h1      = (float*)(csr_src + 800000);   // 50000*128

    // ---- build CSR (shared by both layers) ----
    hipMemsetAsync(degi, 0, 50048 * sizeof(int), stream);
    hist_kernel<<<(N_EDGES + 255) / 256, 256, 0, stream>>>(dst, degi);
    scan_kernel<<<1, SCAN_THREADS, 0, stream>>>(degi, offsets, cursor);
    fill_kernel<<<(N_EDGES + 255) / 256, 256, 0, stream>>>(src, dst, cursor, csr_src);

    // ---- layer 1: h1 = relu(x@Ws1 + mean_neigh(x)@Wn1 + b1) ----
    sage_fused_kernel<N_FEAT, N_HIDDEN, true>
        <<<N_NODES / 8, 256, 0, stream>>>(x, offsets, csr_src,
                                          W_self1, W_neigh1, b1, h1);

    // ---- layer 2: out = h1@Ws2 + mean_neigh(h1)@Wn2 + b2 ----
    sage_fused_kernel<N_HIDDEN, N_CLASSES, false>
        <<<N_NODES / 16, 256, 0, stream>>>(h1, offsets, csr_src,
                                           W_self2, W_neigh2, b2, out);
}

// Round 3
// 478.317 us; speedup vs baseline: 2.3099x; 1.3444x over previous
//
#include <hip/hip_runtime.h>

#define N_NODES 50000
#define N_EDGES 800000
#define N_FEAT 128
#define N_HIDDEN 128
#define N_CLASSES 64

#define SCAN_THREADS 1024
#define SCAN_CHUNK 49  // ceil(50000/1024)

// ---------------- bf16 helpers (RNE pack, shift unpack) ----------------
__device__ __forceinline__ unsigned short f32_to_bf16(float f) {
    unsigned int u = __float_as_uint(f);
    return (unsigned short)((u + 0x7fffu + ((u >> 16) & 1u)) >> 16);
}
__device__ __forceinline__ float bf16lo(unsigned int v) { return __uint_as_float(v << 16); }
__device__ __forceinline__ float bf16hi(unsigned int v) { return __uint_as_float(v & 0xffff0000u); }

// ---------------------------------------------------------------------------
// CSR build
// ---------------------------------------------------------------------------
__global__ void hist_kernel(const int* __restrict__ dst, int* __restrict__ degi) {
    int e = blockIdx.x * blockDim.x + threadIdx.x;
    if (e < N_EDGES) atomicAdd(&degi[dst[e]], 1);
}

__global__ void scan_kernel(const int* __restrict__ degi,
                            int* __restrict__ offsets,
                            int* __restrict__ cursor) {
    __shared__ int partial[SCAN_THREADS];
    const int t = threadIdx.x;
    const int lo = t * SCAN_CHUNK;
    const int hi = min(lo + SCAN_CHUNK, N_NODES);

    int total = 0;
    for (int i = lo; i < hi; ++i) total += degi[i];
    partial[t] = total;
    __syncthreads();
    for (int s = 1; s < SCAN_THREADS; s <<= 1) {
        int v = (t >= s) ? partial[t - s] : 0;
        __syncthreads();
        partial[t] += v;
        __syncthreads();
    }
    int base = (t == 0) ? 0 : partial[t - 1];
    int run = base;
    for (int i = lo; i < hi; ++i) {
        offsets[i] = run;
        cursor[i] = run;
        run += degi[i];
    }
    if (hi == N_NODES && hi > lo) offsets[N_NODES] = run;
}

__global__ void fill_kernel(const int* __restrict__ src, const int* __restrict__ dst,
                            int* __restrict__ cursor, int* __restrict__ csr_src) {
    int e = blockIdx.x * blockDim.x + threadIdx.x;
    if (e < N_EDGES) {
        int pos = atomicAdd(&cursor[dst[e]], 1);
        csr_src[pos] = src[e];
    }
}

// ---------------------------------------------------------------------------
// Dual GEMM: s[n,:] = x[n,:]@Wself + b (fp32);  p[n,:] = x[n,:]@Wneigh (bf16)
// 256 threads, NPB=32 nodes/block, each thread: 1 float4 column x SLOTS nodes.
// W loads amortized SLOTS x vs one-node-per-thread.
// ---------------------------------------------------------------------------
template <int IN, int OUT, int SLOTS>
__global__ __launch_bounds__(256) void gemm_dual_kernel(
        const float* __restrict__ xin,
        const float* __restrict__ Wself,
        const float* __restrict__ Wneigh,
        const float* __restrict__ bias,
        float* __restrict__ s,
        unsigned short* __restrict__ p) {
    constexpr int TPN = OUT / 4;           // float4 columns
    constexpr int TROWS = 256 / TPN;       // thread-rows per block
    constexpr int NPB = TROWS * SLOTS;     // nodes per block (32)
    constexpr int LDW = IN + 4;            // padded LDS stride (keeps 16B align)

    __shared__ float xs[NPB][LDW];
    const int tid = threadIdx.x;
    const int nodeBase = blockIdx.x * NPB;

    // stage x rows (float4, clamp OOB rows; their results are never stored)
    for (int idx = tid; idx < NPB * (IN / 4); idx += 256) {
        int r = idx / (IN / 4);
        int c = idx % (IN / 4);
        int node = nodeBase + r;
        if (node >= N_NODES) node = N_NODES - 1;
        float4 v = ((const float4*)xin)[(size_t)node * (IN / 4) + c];
        *(float4*)&xs[r][c * 4] = v;
    }
    __syncthreads();

    const int c4 = tid % TPN;
    const int row0 = (tid / TPN) * SLOTS;

    const float4* Ws4 = (const float4*)Wself;   // [IN][TPN]
    const float4* Wn4 = (const float4*)Wneigh;
    const float4 bv = ((const float4*)bias)[c4];

    float4 accS[SLOTS], accP[SLOTS];
#pragma unroll
    for (int j = 0; j < SLOTS; ++j) {
        accS[j] = bv;
        accP[j] = make_float4(0.f, 0.f, 0.f, 0.f);
    }

#pragma unroll 4
    for (int k = 0; k < IN; ++k) {
        const float4 w1 = Ws4[k * TPN + c4];
        const float4 w2 = Wn4[k * TPN + c4];
#pragma unroll
        for (int j = 0; j < SLOTS; ++j) {
            const float xv = xs[row0 + j][k];
            accS[j].x += xv * w1.x; accS[j].y += xv * w1.y;
            accS[j].z += xv * w1.z; accS[j].w += xv * w1.w;
            accP[j].x += xv * w2.x; accP[j].y += xv * w2.y;
            accP[j].z += xv * w2.z; accP[j].w += xv * w2.w;
        }
    }

#pragma unroll
    for (int j = 0; j < SLOTS; ++j) {
        const int node = nodeBase + row0 + j;
        if (node < N_NODES) {
            ((float4*)s)[(size_t)node * TPN + c4] = accS[j];
            ushort4 pv;
            pv.x = f32_to_bf16(accP[j].x);
            pv.y = f32_to_bf16(accP[j].y);
            pv.z = f32_to_bf16(accP[j].z);
            pv.w = f32_to_bf16(accP[j].w);
            ((ushort4*)p)[(size_t)node * TPN + c4] = pv;
        }
    }
}

// ---------------------------------------------------------------------------
// Aggregate, F=128, wave per node: h[n,:] = relu(h[n,:] + mean_{s in N(n)} p[s,:])
// p rows are 256B bf16; lane reads one uint (2 bf16). In-place over s.
// ---------------------------------------------------------------------------
__global__ __launch_bounds__(256) void agg_relu_128_kernel(
        const unsigned short* __restrict__ p,
        const int* __restrict__ offsets,
        const int* __restrict__ csr_src,
        float* __restrict__ h) {
    const int wave = threadIdx.x >> 6;
    const int lane = threadIdx.x & 63;
    const int node = blockIdx.x * 4 + wave;
    if (node >= N_NODES) return;

    const int off0 = offsets[node];
    const int off1 = offsets[node + 1];
    const unsigned int* pp = (const unsigned int*)p;   // [N][64] uints

    float ax = 0.f, ay = 0.f;
    int i = off0;
    for (; i + 8 <= off1; i += 8) {
        unsigned int v0 = pp[(size_t)csr_src[i + 0] * 64 + lane];
        unsigned int v1 = pp[(size_t)csr_src[i + 1] * 64 + lane];
        unsigned int v2 = pp[(size_t)csr_src[i + 2] * 64 + lane];
        unsigned int v3 = pp[(size_t)csr_src[i + 3] * 64 + lane];
        unsigned int v4 = pp[(size_t)csr_src[i + 4] * 64 + lane];
        unsigned int v5 = pp[(size_t)csr_src[i + 5] * 64 + lane];
        unsigned int v6 = pp[(size_t)csr_src[i + 6] * 64 + lane];
        unsigned int v7 = pp[(size_t)csr_src[i + 7] * 64 + lane];
        ax += bf16lo(v0) + bf16lo(v1) + bf16lo(v2) + bf16lo(v3)
            + bf16lo(v4) + bf16lo(v5) + bf16lo(v6) + bf16lo(v7);
        ay += bf16hi(v0) + bf16hi(v1) + bf16hi(v2) + bf16hi(v3)
            + bf16hi(v4) + bf16hi(v5) + bf16hi(v6) + bf16hi(v7);
    }
    for (; i < off1; ++i) {
        unsigned int v = pp[(size_t)csr_src[i] * 64 + lane];
        ax += bf16lo(v);
        ay += bf16hi(v);
    }
    const float invdeg = 1.0f / fmaxf((float)(off1 - off0), 1.0f);
    float2 sv = *(float2*)&h[(size_t)node * 128 + lane * 2];
    sv.x = fmaxf(sv.x + ax * invdeg, 0.f);
    sv.y = fmaxf(sv.y + ay * invdeg, 0.f);
    *(float2*)&h[(size_t)node * 128 + lane * 2] = sv;
}

// ---------------------------------------------------------------------------
// Aggregate, F=64, half-wave per node: out[n,:] += mean p[s,:]  (no relu)
// p rows are 128B bf16; 32 lanes x uint. In-place over s2 (= d_out).
// ---------------------------------------------------------------------------
__global__ __launch_bounds__(256) void agg_64_kernel(
        const unsigned short* __restrict__ p,
        const int* __restrict__ offsets,
        const int* __restrict__ csr_src,
        float* __restrict__ out) {
    const int hw = threadIdx.x >> 5;      // 0..7
    const int l = threadIdx.x & 31;
    const int node = blockIdx.x * 8 + hw;
    if (node >= N_NODES) return;

    const int off0 = offsets[node];
    const int off1 = offsets[node + 1];
    const unsigned int* pp = (const unsigned int*)p;   // [N][32] uints

    float ax = 0.f, ay = 0.f;
    int i = off0;
    for (; i + 8 <= off1; i += 8) {
        unsigned int v0 = pp[(size_t)csr_src[i + 0] * 32 + l];
        unsigned int v1 = pp[(size_t)csr_src[i + 1] * 32 + l];
        unsigned int v2 = pp[(size_t)csr_src[i + 2] * 32 + l];
        unsigned int v3 = pp[(size_t)csr_src[i + 3] * 32 + l];
        unsigned int v4 = pp[(size_t)csr_src[i + 4] * 32 + l];
        unsigned int v5 = pp[(size_t)csr_src[i + 5] * 32 + l];
        unsigned int v6 = pp[(size_t)csr_src[i + 6] * 32 + l];
        unsigned int v7 = pp[(size_t)csr_src[i + 7] * 32 + l];
        ax += bf16lo(v0) + bf16lo(v1) + bf16lo(v2) + bf16lo(v3)
            + bf16lo(v4) + bf16lo(v5) + bf16lo(v6) + bf16lo(v7);
        ay += bf16hi(v0) + bf16hi(v1) + bf16hi(v2) + bf16hi(v3)
            + bf16hi(v4) + bf16hi(v5) + bf16hi(v6) + bf16hi(v7);
    }
    for (; i < off1; ++i) {
        unsigned int v = pp[(size_t)csr_src[i] * 32 + l];
        ax += bf16lo(v);
        ay += bf16hi(v);
    }
    const float invdeg = 1.0f / fmaxf((float)(off1 - off0), 1.0f);
    float2 sv = *(float2*)&out[(size_t)node * 64 + l * 2];
    sv.x += ax * invdeg;
    sv.y += ay * invdeg;
    *(float2*)&out[(size_t)node * 64 + l * 2] = sv;
}

extern "C" void kernel_launch(void* const* d_in, const int* in_sizes, int n_in,
                              void* d_out, int out_size, void* d_ws, size_t ws_size,
                              hipStream_t stream) {
    const float* x        = (const float*)d_in[0];
    const float* W_self1  = (const float*)d_in[1];
    const float* W_neigh1 = (const float*)d_in[2];
    const float* b1       = (const float*)d_in[3];
    const float* W_self2  = (const float*)d_in[4];
    const float* W_neigh2 = (const float*)d_in[5];
    const float* b2       = (const float*)d_in[6];
    const int*   src      = (const int*)d_in[7];
    const int*   dst      = (const int*)d_in[8];
    float* out = (float*)d_out;

    // workspace (4B units):
    int*   degi    = (int*)d_ws;                    // 50048
    int*   offsets = degi + 50048;                  // 50048
    int*   cursor  = offsets + 50048;               // 50048
    int*   csr_src = cursor + 50048;                // 800000
    float* s1      = (float*)(csr_src + 800000);    // 50000*128 fp32 (-> h1 in place)
    unsigned short* p1 = (unsigned short*)(s1 + (size_t)N_NODES * N_HIDDEN);  // 50000*128 bf16
    unsigned short* p2 = p1 + (size_t)N_NODES * N_HIDDEN;                      // 50000*64 bf16
    // total: ~48.6 MB

    // ---- CSR (shared by both layers) ----
    hipMemsetAsync(degi, 0, 50048 * sizeof(int), stream);
    hist_kernel<<<(N_EDGES + 255) / 256, 256, 0, stream>>>(dst, degi);
    scan_kernel<<<1, SCAN_THREADS, 0, stream>>>(degi, offsets, cursor);
    fill_kernel<<<(N_EDGES + 255) / 256, 256, 0, stream>>>(src, dst, cursor, csr_src);

    // ---- layer 1 ----
    // s1 = x@Ws1+b1 (fp32); p1 = x@Wn1 (bf16)
    gemm_dual_kernel<N_FEAT, N_HIDDEN, 4>
        <<<(N_NODES + 31) / 32, 256, 0, stream>>>(x, W_self1, W_neigh1, b1, s1, p1);
    // h1 = relu(s1 + mean gather(p1)), in place over s1
    agg_relu_128_kernel<<<(N_NODES + 3) / 4, 256, 0, stream>>>(p1, offsets, csr_src, s1);

    // ---- layer 2 ----
    // s2 = h1@Ws2+b2 -> written directly into d_out; p2 = h1@Wn2 (bf16)
    gemm_dual_kernel<N_HIDDEN, N_CLASSES, 2>
        <<<(N_NODES + 31) / 32, 256, 0, stream>>>(s1, W_self2, W_neigh2, b2, out, p2);
    // out += mean gather(p2), in place
    agg_64_kernel<<<(N_NODES + 7) / 8, 256, 0, stream>>>(p2, offsets, csr_src, out);
}

// Round 4
// 367.536 us; speedup vs baseline: 3.0062x; 1.3014x over previous
//
#include <hip/hip_runtime.h>

#define N_NODES 50000
#define N_EDGES 800000
#define N_FEAT 128
#define N_HIDDEN 128
#define N_CLASSES 64

#define SCAN_CHUNK 1024
#define SCAN_NBLK ((N_NODES + SCAN_CHUNK - 1) / SCAN_CHUNK)  // 49

// ---------------- bf16 helpers (RNE pack, shift unpack) ----------------
__device__ __forceinline__ unsigned short f32_to_bf16(float f) {
    unsigned int u = __float_as_uint(f);
    return (unsigned short)((u + 0x7fffu + ((u >> 16) & 1u)) >> 16);
}
__device__ __forceinline__ float bf16lo(unsigned int v) { return __uint_as_float(v << 16); }
__device__ __forceinline__ float bf16hi(unsigned int v) { return __uint_as_float(v & 0xffff0000u); }

// ---------------------------------------------------------------------------
// CSR build
// ---------------------------------------------------------------------------
__global__ void hist_kernel(const int* __restrict__ dst, int* __restrict__ degi) {
    int e = blockIdx.x * blockDim.x + threadIdx.x;
    if (e < N_EDGES) atomicAdd(&degi[dst[e]], 1);
}

// scan step 1: per-block (1024 elems, 256 thr x 4) partial sums
__global__ __launch_bounds__(256) void scan1_kernel(const int* __restrict__ degi,
                                                    int* __restrict__ bsum) {
    __shared__ int red[256];
    const int t = threadIdx.x;
    const int base = blockIdx.x * SCAN_CHUNK + t * 4;
    int s = 0;
#pragma unroll
    for (int j = 0; j < 4; ++j) {
        int i = base + j;
        if (i < N_NODES) s += degi[i];
    }
    red[t] = s;
    __syncthreads();
    for (int st = 128; st > 0; st >>= 1) {
        if (t < st) red[t] += red[t + st];
        __syncthreads();
    }
    if (t == 0) bsum[blockIdx.x] = red[0];
}

// scan step 2: exclusive scan of the 49 block sums (one wave)
__global__ void scan2_kernel(const int* __restrict__ bsum, int* __restrict__ bof) {
    const int t = threadIdx.x;  // 0..63
    int orig = (t < SCAN_NBLK) ? bsum[t] : 0;
    int v = orig;
    for (int s = 1; s < 64; s <<= 1) {
        int u = __shfl_up(v, s);
        if (t >= s) v += u;
    }
    if (t < SCAN_NBLK) bof[t] = v - orig;  // exclusive
}

// scan step 3: local scan within each 1024-chunk + block offset -> offsets, cursor
__global__ __launch_bounds__(256) void scan3_kernel(const int* __restrict__ degi,
                                                    const int* __restrict__ bof,
                                                    int* __restrict__ offsets,
                                                    int* __restrict__ cursor) {
    __shared__ int part[256];
    const int t = threadIdx.x;
    const int base = blockIdx.x * SCAN_CHUNK + t * 4;

    int loc[4];
    int s = 0;
#pragma unroll
    for (int j = 0; j < 4; ++j) {
        int i = base + j;
        loc[j] = (i < N_NODES) ? degi[i] : 0;
        s += loc[j];
    }
    part[t] = s;
    __syncthreads();
    // Hillis-Steele inclusive scan over 256 thread sums
    for (int st = 1; st < 256; st <<= 1) {
        int v = (t >= st) ? part[t - st] : 0;
        __syncthreads();
        part[t] += v;
        __syncthreads();
    }
    int run = bof[blockIdx.x] + part[t] - s;  // exclusive thread prefix
#pragma unroll
    for (int j = 0; j < 4; ++j) {
        int i = base + j;
        if (i < N_NODES) {
            offsets[i] = run;
            cursor[i] = run;
            run += loc[j];
        }
    }
    if (blockIdx.x == 0 && t == 0) offsets[N_NODES] = N_EDGES;  // sentinel
}

__global__ void fill_kernel(const int* __restrict__ src, const int* __restrict__ dst,
                            int* __restrict__ cursor, int* __restrict__ csr_src) {
    int e = blockIdx.x * blockDim.x + threadIdx.x;
    if (e < N_EDGES) {
        int pos = atomicAdd(&cursor[dst[e]], 1);
        csr_src[pos] = src[e];
    }
}

// ---------------------------------------------------------------------------
// Dual GEMM: s[n,:] = x[n,:]@Wself + b (fp32);  p[n,:] = x[n,:]@Wneigh (bf16)
// ---------------------------------------------------------------------------
template <int IN, int OUT, int SLOTS>
__global__ __launch_bounds__(256) void gemm_dual_kernel(
        const float* __restrict__ xin,
        const float* __restrict__ Wself,
        const float* __restrict__ Wneigh,
        const float* __restrict__ bias,
        float* __restrict__ s,
        unsigned short* __restrict__ p) {
    constexpr int TPN = OUT / 4;           // float4 columns
    constexpr int TROWS = 256 / TPN;       // thread-rows per block
    constexpr int NPB = TROWS * SLOTS;     // nodes per block (32)
    constexpr int LDW = IN + 4;            // padded LDS stride (keeps 16B align)

    __shared__ float xs[NPB][LDW];
    const int tid = threadIdx.x;
    const int nodeBase = blockIdx.x * NPB;

    for (int idx = tid; idx < NPB * (IN / 4); idx += 256) {
        int r = idx / (IN / 4);
        int c = idx % (IN / 4);
        int node = nodeBase + r;
        if (node >= N_NODES) node = N_NODES - 1;
        float4 v = ((const float4*)xin)[(size_t)node * (IN / 4) + c];
        *(float4*)&xs[r][c * 4] = v;
    }
    __syncthreads();

    const int c4 = tid % TPN;
    const int row0 = (tid / TPN) * SLOTS;

    const float4* Ws4 = (const float4*)Wself;   // [IN][TPN]
    const float4* Wn4 = (const float4*)Wneigh;
    const float4 bv = ((const float4*)bias)[c4];

    float4 accS[SLOTS], accP[SLOTS];
#pragma unroll
    for (int j = 0; j < SLOTS; ++j) {
        accS[j] = bv;
        accP[j] = make_float4(0.f, 0.f, 0.f, 0.f);
    }

#pragma unroll 4
    for (int k = 0; k < IN; ++k) {
        const float4 w1 = Ws4[k * TPN + c4];
        const float4 w2 = Wn4[k * TPN + c4];
#pragma unroll
        for (int j = 0; j < SLOTS; ++j) {
            const float xv = xs[row0 + j][k];
            accS[j].x += xv * w1.x; accS[j].y += xv * w1.y;
            accS[j].z += xv * w1.z; accS[j].w += xv * w1.w;
            accP[j].x += xv * w2.x; accP[j].y += xv * w2.y;
            accP[j].z += xv * w2.z; accP[j].w += xv * w2.w;
        }
    }

#pragma unroll
    for (int j = 0; j < SLOTS; ++j) {
        const int node = nodeBase + row0 + j;
        if (node < N_NODES) {
            ((float4*)s)[(size_t)node * TPN + c4] = accS[j];
            ushort4 pv;
            pv.x = f32_to_bf16(accP[j].x);
            pv.y = f32_to_bf16(accP[j].y);
            pv.z = f32_to_bf16(accP[j].z);
            pv.w = f32_to_bf16(accP[j].w);
            ((ushort4*)p)[(size_t)node * TPN + c4] = pv;
        }
    }
}

// ---------------------------------------------------------------------------
// Aggregate, F=128: wave per node, half-wave per neighbor stream.
// Lane = (half, l): reads uint2 (8B = 4 bf16) at p-row[s]*32 + l.
// Half 0 takes neighbors off0+0,2,4..., half 1 takes off0+1,3,5...
// Final shfl_xor(32) merges halves; half 0 writes float4.
// h[n,:] = relu(h[n,:] + mean)  in place.
// ---------------------------------------------------------------------------
__global__ __launch_bounds__(256) void agg_relu_128_kernel(
        const unsigned short* __restrict__ p,
        const int* __restrict__ offsets,
        const int* __restrict__ csr_src,
        float* __restrict__ h) {
    const int wave = threadIdx.x >> 6;
    const int lane = threadIdx.x & 63;
    const int half = lane >> 5;
    const int l = lane & 31;
    const int node = blockIdx.x * 4 + wave;
    if (node >= N_NODES) return;

    const int off0 = offsets[node];
    const int off1 = offsets[node + 1];
    const uint2* pp = (const uint2*)p;   // row stride 32 uint2

    float a0 = 0.f, a1 = 0.f, a2 = 0.f, a3 = 0.f;
    int i = off0 + half;
    for (; i + 6 < off1; i += 8) {   // 4 neighbors per half per iter
        uint2 v0 = pp[(size_t)csr_src[i + 0] * 32 + l];
        uint2 v1 = pp[(size_t)csr_src[i + 2] * 32 + l];
        uint2 v2 = pp[(size_t)csr_src[i + 4] * 32 + l];
        uint2 v3 = pp[(size_t)csr_src[i + 6] * 32 + l];
        a0 += bf16lo(v0.x) + bf16lo(v1.x) + bf16lo(v2.x) + bf16lo(v3.x);
        a1 += bf16hi(v0.x) + bf16hi(v1.x) + bf16hi(v2.x) + bf16hi(v3.x);
        a2 += bf16lo(v0.y) + bf16lo(v1.y) + bf16lo(v2.y) + bf16lo(v3.y);
        a3 += bf16hi(v0.y) + bf16hi(v1.y) + bf16hi(v2.y) + bf16hi(v3.y);
    }
    for (; i < off1; i += 2) {
        uint2 v = pp[(size_t)csr_src[i] * 32 + l];
        a0 += bf16lo(v.x);
        a1 += bf16hi(v.x);
        a2 += bf16lo(v.y);
        a3 += bf16hi(v.y);
    }
    // merge the two half-wave partials (feature group is the same for lane l)
    a0 += __shfl_xor(a0, 32);
    a1 += __shfl_xor(a1, 32);
    a2 += __shfl_xor(a2, 32);
    a3 += __shfl_xor(a3, 32);

    if (half == 0) {
        const float invdeg = 1.0f / fmaxf((float)(off1 - off0), 1.0f);
        float4 sv = ((float4*)h)[(size_t)node * 32 + l];
        sv.x = fmaxf(sv.x + a0 * invdeg, 0.f);
        sv.y = fmaxf(sv.y + a1 * invdeg, 0.f);
        sv.z = fmaxf(sv.z + a2 * invdeg, 0.f);
        sv.w = fmaxf(sv.w + a3 * invdeg, 0.f);
        ((float4*)h)[(size_t)node * 32 + l] = sv;
    }
}

// ---------------------------------------------------------------------------
// Aggregate, F=64: wave per node, quarter-wave per neighbor stream.
// Lane = (q, l): reads uint2 at p-row[s]*16 + l. Quarter q takes neighbors
// off0+q, +4, ... Final shfl_xor(16)+(32); q==0 writes float4 (no relu).
// ---------------------------------------------------------------------------
__global__ __launch_bounds__(256) void agg_64_kernel(
        const unsigned short* __restrict__ p,
        const int* __restrict__ offsets,
        const int* __restrict__ csr_src,
        float* __restrict__ out) {
    const int wave = threadIdx.x >> 6;
    const int lane = threadIdx.x & 63;
    const int q = lane >> 4;
    const int l = lane & 15;
    const int node = blockIdx.x * 4 + wave;
    if (node >= N_NODES) return;

    const int off0 = offsets[node];
    const int off1 = offsets[node + 1];
    const uint2* pp = (const uint2*)p;   // row stride 16 uint2

    float a0 = 0.f, a1 = 0.f, a2 = 0.f, a3 = 0.f;
    int i = off0 + q;
    for (; i + 4 < off1; i += 8) {   // 2 neighbors per quarter per iter
        uint2 v0 = pp[(size_t)csr_src[i + 0] * 16 + l];
        uint2 v1 = pp[(size_t)csr_src[i + 4] * 16 + l];
        a0 += bf16lo(v0.x) + bf16lo(v1.x);
        a1 += bf16hi(v0.x) + bf16hi(v1.x);
        a2 += bf16lo(v0.y) + bf16lo(v1.y);
        a3 += bf16hi(v0.y) + bf16hi(v1.y);
    }
    for (; i < off1; i += 4) {
        uint2 v = pp[(size_t)csr_src[i] * 16 + l];
        a0 += bf16lo(v.x);
        a1 += bf16hi(v.x);
        a2 += bf16lo(v.y);
        a3 += bf16hi(v.y);
    }
    a0 += __shfl_xor(a0, 16); a0 += __shfl_xor(a0, 32);
    a1 += __shfl_xor(a1, 16); a1 += __shfl_xor(a1, 32);
    a2 += __shfl_xor(a2, 16); a2 += __shfl_xor(a2, 32);
    a3 += __shfl_xor(a3, 16); a3 += __shfl_xor(a3, 32);

    if (q == 0) {
        const float invdeg = 1.0f / fmaxf((float)(off1 - off0), 1.0f);
        float4 sv = ((float4*)out)[(size_t)node * 16 + l];
        sv.x += a0 * invdeg;
        sv.y += a1 * invdeg;
        sv.z += a2 * invdeg;
        sv.w += a3 * invdeg;
        ((float4*)out)[(size_t)node * 16 + l] = sv;
    }
}

extern "C" void kernel_launch(void* const* d_in, const int* in_sizes, int n_in,
                              void* d_out, int out_size, void* d_ws, size_t ws_size,
                              hipStream_t stream) {
    const float* x        = (const float*)d_in[0];
    const float* W_self1  = (const float*)d_in[1];
    const float* W_neigh1 = (const float*)d_in[2];
    const float* b1       = (const float*)d_in[3];
    const float* W_self2  = (const float*)d_in[4];
    const float* W_neigh2 = (const float*)d_in[5];
    const float* b2       = (const float*)d_in[6];
    const int*   src      = (const int*)d_in[7];
    const int*   dst      = (const int*)d_in[8];
    float* out = (float*)d_out;

    // workspace (4B units):
    int*   degi    = (int*)d_ws;                    // 50048
    int*   offsets = degi + 50048;                  // 50048
    int*   cursor  = offsets + 50048;               // 50048
    int*   csr_src = cursor + 50048;                // 800000
    int*   bsum    = csr_src + 800000;              // 64
    int*   bof     = bsum + 64;                     // 64
    float* s1      = (float*)(bof + 64 + 64);       // 50000*128 fp32 (-> h1 in place)
    unsigned short* p1 = (unsigned short*)(s1 + (size_t)N_NODES * N_HIDDEN);  // 50000*128 bf16
    unsigned short* p2 = p1 + (size_t)N_NODES * N_HIDDEN;                      // 50000*64 bf16

    // ---- CSR (shared by both layers) ----
    hipMemsetAsync(degi, 0, 50048 * sizeof(int), stream);
    hist_kernel<<<(N_EDGES + 255) / 256, 256, 0, stream>>>(dst, degi);
    scan1_kernel<<<SCAN_NBLK, 256, 0, stream>>>(degi, bsum);
    scan2_kernel<<<1, 64, 0, stream>>>(bsum, bof);
    scan3_kernel<<<SCAN_NBLK, 256, 0, stream>>>(degi, bof, offsets, cursor);
    fill_kernel<<<(N_EDGES + 255) / 256, 256, 0, stream>>>(src, dst, cursor, csr_src);

    // ---- layer 1 ----
    gemm_dual_kernel<N_FEAT, N_HIDDEN, 4>
        <<<(N_NODES + 31) / 32, 256, 0, stream>>>(x, W_self1, W_neigh1, b1, s1, p1);
    agg_relu_128_kernel<<<(N_NODES + 3) / 4, 256, 0, stream>>>(p1, offsets, csr_src, s1);

    // ---- layer 2 ----
    gemm_dual_kernel<N_HIDDEN, N_CLASSES, 2>
        <<<(N_NODES + 31) / 32, 256, 0, stream>>>(s1, W_self2, W_neigh2, b2, out, p2);
    agg_64_kernel<<<(N_NODES + 3) / 4, 256, 0, stream>>>(p2, offsets, csr_src, out);
}

// Round 5
// 277.551 us; speedup vs baseline: 3.9808x; 1.3242x over previous
//
#include <hip/hip_runtime.h>

#define N_NODES 50000
#define N_EDGES 800000
#define N_FEAT 128
#define N_HIDDEN 128
#define N_CLASSES 64

#define SCAN_CHUNK 1024
#define SCAN_NBLK ((N_NODES + SCAN_CHUNK - 1) / SCAN_CHUNK)  // 49

typedef __attribute__((ext_vector_type(8))) short bf16x8;
typedef __attribute__((ext_vector_type(4))) float f32x4;

// ---------------- bf16 helpers (RNE pack, shift unpack) ----------------
__device__ __forceinline__ unsigned short f32_to_bf16(float f) {
    unsigned int u = __float_as_uint(f);
    return (unsigned short)((u + 0x7fffu + ((u >> 16) & 1u)) >> 16);
}
__device__ __forceinline__ float bf16lo(unsigned int v) { return __uint_as_float(v << 16); }
__device__ __forceinline__ float bf16hi(unsigned int v) { return __uint_as_float(v & 0xffff0000u); }

// ---------------------------------------------------------------------------
// CSR build
// ---------------------------------------------------------------------------
__global__ void hist_kernel(const int* __restrict__ dst, int* __restrict__ degi) {
    int e = blockIdx.x * blockDim.x + threadIdx.x;
    if (e < N_EDGES) atomicAdd(&degi[dst[e]], 1);
}

__global__ __launch_bounds__(256) void scan1_kernel(const int* __restrict__ degi,
                                                    int* __restrict__ bsum) {
    __shared__ int red[256];
    const int t = threadIdx.x;
    const int base = blockIdx.x * SCAN_CHUNK + t * 4;
    int s = 0;
#pragma unroll
    for (int j = 0; j < 4; ++j) {
        int i = base + j;
        if (i < N_NODES) s += degi[i];
    }
    red[t] = s;
    __syncthreads();
    for (int st = 128; st > 0; st >>= 1) {
        if (t < st) red[t] += red[t + st];
        __syncthreads();
    }
    if (t == 0) bsum[blockIdx.x] = red[0];
}

__global__ void scan2_kernel(const int* __restrict__ bsum, int* __restrict__ bof) {
    const int t = threadIdx.x;  // 0..63
    int orig = (t < SCAN_NBLK) ? bsum[t] : 0;
    int v = orig;
    for (int s = 1; s < 64; s <<= 1) {
        int u = __shfl_up(v, s);
        if (t >= s) v += u;
    }
    if (t < SCAN_NBLK) bof[t] = v - orig;  // exclusive
}

__global__ __launch_bounds__(256) void scan3_kernel(const int* __restrict__ degi,
                                                    const int* __restrict__ bof,
                                                    int* __restrict__ offsets,
                                                    int* __restrict__ cursor) {
    __shared__ int part[256];
    const int t = threadIdx.x;
    const int base = blockIdx.x * SCAN_CHUNK + t * 4;

    int loc[4];
    int s = 0;
#pragma unroll
    for (int j = 0; j < 4; ++j) {
        int i = base + j;
        loc[j] = (i < N_NODES) ? degi[i] : 0;
        s += loc[j];
    }
    part[t] = s;
    __syncthreads();
    for (int st = 1; st < 256; st <<= 1) {
        int v = (t >= st) ? part[t - st] : 0;
        __syncthreads();
        part[t] += v;
        __syncthreads();
    }
    int run = bof[blockIdx.x] + part[t] - s;
#pragma unroll
    for (int j = 0; j < 4; ++j) {
        int i = base + j;
        if (i < N_NODES) {
            offsets[i] = run;
            cursor[i] = run;
            run += loc[j];
        }
    }
    if (blockIdx.x == 0 && t == 0) offsets[N_NODES] = N_EDGES;
}

__global__ void fill_kernel(const int* __restrict__ src, const int* __restrict__ dst,
                            int* __restrict__ cursor, int* __restrict__ csr_src) {
    int e = blockIdx.x * blockDim.x + threadIdx.x;
    if (e < N_EDGES) {
        int pos = atomicAdd(&cursor[dst[e]], 1);
        csr_src[pos] = src[e];
    }
}

// ---------------------------------------------------------------------------
// Prep: cast x (fp32) -> xb (bf16), vectorized 4 elems/thread
// ---------------------------------------------------------------------------
__global__ __launch_bounds__(256) void cast_bf16_kernel(const float* __restrict__ x,
                                                        unsigned short* __restrict__ xb,
                                                        int n4) {
    int i = blockIdx.x * blockDim.x + threadIdx.x;
    if (i < n4) {
        float4 v = ((const float4*)x)[i];
        ushort4 o;
        o.x = f32_to_bf16(v.x);
        o.y = f32_to_bf16(v.y);
        o.z = f32_to_bf16(v.z);
        o.w = f32_to_bf16(v.w);
        ((ushort4*)xb)[i] = o;
    }
}

// ---------------------------------------------------------------------------
// Prep: pack [Wself | Wneigh] (fp32, row-major [K=128][NO]) into bf16 MFMA
// B-fragment order: Bp[((t*NT + c)*64 + lane)*8 + j] = W[k][n],
//   k = 32t + (lane>>4)*8 + j,  n = 16c + (lane&15)  (n >= NO -> Wneigh col n-NO)
// ---------------------------------------------------------------------------
template <int NOUT>
__global__ __launch_bounds__(256) void pack_w_kernel(const float* __restrict__ Wself,
                                                     const float* __restrict__ Wneigh,
                                                     unsigned short* __restrict__ Bp) {
    constexpr int NT = NOUT / 16;
    constexpr int NO = NOUT / 2;
    const int idx = blockIdx.x * 256 + threadIdx.x;   // one thread per (t,c,lane)
    if (idx >= 4 * NT * 64) return;
    const int lane = idx & 63;
    const int tc = idx >> 6;
    const int c = tc % NT;
    const int t = tc / NT;
    const int n = c * 16 + (lane & 15);
    const int k0 = t * 32 + (lane >> 4) * 8;
    const float* W = (n < NO) ? Wself : Wneigh;
    const int nn = (n < NO) ? n : n - NO;
    ushort4 lo, hi;
    lo.x = f32_to_bf16(W[(k0 + 0) * NO + nn]);
    lo.y = f32_to_bf16(W[(k0 + 1) * NO + nn]);
    lo.z = f32_to_bf16(W[(k0 + 2) * NO + nn]);
    lo.w = f32_to_bf16(W[(k0 + 3) * NO + nn]);
    hi.x = f32_to_bf16(W[(k0 + 4) * NO + nn]);
    hi.y = f32_to_bf16(W[(k0 + 5) * NO + nn]);
    hi.z = f32_to_bf16(W[(k0 + 6) * NO + nn]);
    hi.w = f32_to_bf16(W[(k0 + 7) * NO + nn]);
    ((ushort4*)&Bp[(size_t)idx * 8])[0] = lo;
    ((ushort4*)&Bp[(size_t)idx * 8])[1] = hi;
}

// ---------------------------------------------------------------------------
// MFMA dual GEMM: for 32 nodes/block, computes [xb @ Wself | xb @ Wneigh].
// Columns < NO -> s (fp32, +bias); columns >= NO -> p (bf16).
// 4 waves; wave w owns n-tiles [w*NSUB, (w+1)*NSUB). K=128 = 4 MFMA steps.
// A-frag: lane reads xb[mbase + (lane&15)][32t + (lane>>4)*8 ..+7] (16B).
// C/D: col = lane&15 (n), row = (lane>>4)*4 + reg (m).
// ---------------------------------------------------------------------------
template <int NOUT>
__global__ __launch_bounds__(256) void gemm_mfma_kernel(
        const unsigned short* __restrict__ xb,   // [N_NODES][128] bf16
        const unsigned short* __restrict__ Bp,   // packed B frags
        const float* __restrict__ bias,          // [NO]
        float* __restrict__ s,                   // [N_NODES][NO] fp32
        unsigned short* __restrict__ p) {        // [N_NODES][NO] bf16
    constexpr int NT = NOUT / 16;
    constexpr int NO = NOUT / 2;
    constexpr int NSUB = NT / 4;

    const int tid = threadIdx.x;
    const int wave = tid >> 6;
    const int lane = tid & 63;
    const int mcol = lane & 15;       // A: m-row within tile; C/D: n-col within tile
    const int kgrp = lane >> 4;       // A: k-group; C/D: m-row group

    const int mbase = blockIdx.x * 32;
    int r0 = mbase + mcol;       if (r0 >= N_NODES) r0 = N_NODES - 1;
    int r1 = mbase + 16 + mcol;  if (r1 >= N_NODES) r1 = N_NODES - 1;

    f32x4 acc[2][NSUB];
#pragma unroll
    for (int mt = 0; mt < 2; ++mt)
#pragma unroll
        for (int c = 0; c < NSUB; ++c)
            acc[mt][c] = (f32x4){0.f, 0.f, 0.f, 0.f};

#pragma unroll
    for (int t = 0; t < 4; ++t) {
        bf16x8 a0 = *(const bf16x8*)&xb[(size_t)r0 * 128 + t * 32 + kgrp * 8];
        bf16x8 a1 = *(const bf16x8*)&xb[(size_t)r1 * 128 + t * 32 + kgrp * 8];
#pragma unroll
        for (int c = 0; c < NSUB; ++c) {
            const int ct = wave * NSUB + c;
            bf16x8 bfrag = *(const bf16x8*)&Bp[((size_t)(t * NT + ct) * 64 + lane) * 8];
            acc[0][c] = __builtin_amdgcn_mfma_f32_16x16x32_bf16(a0, bfrag, acc[0][c], 0, 0, 0);
            acc[1][c] = __builtin_amdgcn_mfma_f32_16x16x32_bf16(a1, bfrag, acc[1][c], 0, 0, 0);
        }
    }

    // hoist bias per n-tile (0 for the p half)
    float bv[NSUB];
    int ncols[NSUB];
#pragma unroll
    for (int c = 0; c < NSUB; ++c) {
        ncols[c] = (wave * NSUB + c) * 16 + mcol;
        bv[c] = (ncols[c] < NO) ? bias[ncols[c]] : 0.f;
    }

#pragma unroll
    for (int mt = 0; mt < 2; ++mt) {
#pragma unroll
        for (int c = 0; c < NSUB; ++c) {
            const int ncol = ncols[c];
#pragma unroll
            for (int r = 0; r < 4; ++r) {
                const int node = mbase + mt * 16 + kgrp * 4 + r;
                if (node >= N_NODES) continue;
                const float v = acc[mt][c][r];
                if (ncol < NO) {
                    s[(size_t)node * NO + ncol] = v + bv[c];
                } else {
                    p[(size_t)node * NO + (ncol - NO)] = f32_to_bf16(v);
                }
            }
        }
    }
}

// ---------------------------------------------------------------------------
// Aggregate, F=128: wave per node, half-wave per neighbor stream.
// Reads s (fp32 self term), p (bf16 projected), writes h1b (bf16) = relu(s+mean).
// ---------------------------------------------------------------------------
__global__ __launch_bounds__(256) void agg_relu_128_kernel(
        const float* __restrict__ s,
        const unsigned short* __restrict__ p,
        const int* __restrict__ offsets,
        const int* __restrict__ csr_src,
        unsigned short* __restrict__ h1b) {
    const int wave = threadIdx.x >> 6;
    const int lane = threadIdx.x & 63;
    const int half = lane >> 5;
    const int l = lane & 31;
    const int node = blockIdx.x * 4 + wave;
    if (node >= N_NODES) return;

    const int off0 = offsets[node];
    const int off1 = offsets[node + 1];
    const uint2* pp = (const uint2*)p;   // row stride 32 uint2

    float a0 = 0.f, a1 = 0.f, a2 = 0.f, a3 = 0.f;
    int i = off0 + half;
    for (; i + 6 < off1; i += 8) {
        uint2 v0 = pp[(size_t)csr_src[i + 0] * 32 + l];
        uint2 v1 = pp[(size_t)csr_src[i + 2] * 32 + l];
        uint2 v2 = pp[(size_t)csr_src[i + 4] * 32 + l];
        uint2 v3 = pp[(size_t)csr_src[i + 6] * 32 + l];
        a0 += bf16lo(v0.x) + bf16lo(v1.x) + bf16lo(v2.x) + bf16lo(v3.x);
        a1 += bf16hi(v0.x) + bf16hi(v1.x) + bf16hi(v2.x) + bf16hi(v3.x);
        a2 += bf16lo(v0.y) + bf16lo(v1.y) + bf16lo(v2.y) + bf16lo(v3.y);
        a3 += bf16hi(v0.y) + bf16hi(v1.y) + bf16hi(v2.y) + bf16hi(v3.y);
    }
    for (; i < off1; i += 2) {
        uint2 v = pp[(size_t)csr_src[i] * 32 + l];
        a0 += bf16lo(v.x);
        a1 += bf16hi(v.x);
        a2 += bf16lo(v.y);
        a3 += bf16hi(v.y);
    }
    a0 += __shfl_xor(a0, 32);
    a1 += __shfl_xor(a1, 32);
    a2 += __shfl_xor(a2, 32);
    a3 += __shfl_xor(a3, 32);

    if (half == 0) {
        const float invdeg = 1.0f / fmaxf((float)(off1 - off0), 1.0f);
        float4 sv = ((const float4*)s)[(size_t)node * 32 + l];
        ushort4 o;
        o.x = f32_to_bf16(fmaxf(sv.x + a0 * invdeg, 0.f));
        o.y = f32_to_bf16(fmaxf(sv.y + a1 * invdeg, 0.f));
        o.z = f32_to_bf16(fmaxf(sv.z + a2 * invdeg, 0.f));
        o.w = f32_to_bf16(fmaxf(sv.w + a3 * invdeg, 0.f));
        ((ushort4*)h1b)[(size_t)node * 32 + l] = o;
    }
}

// ---------------------------------------------------------------------------
// Aggregate, F=64: wave per node, quarter-wave per neighbor stream.
// out[n,:] += mean p[s,:]  (fp32 in place, no relu)
// ---------------------------------------------------------------------------
__global__ __launch_bounds__(256) void agg_64_kernel(
        const unsigned short* __restrict__ p,
        const int* __restrict__ offsets,
        const int* __restrict__ csr_src,
        float* __restrict__ out) {
    const int wave = threadIdx.x >> 6;
    const int lane = threadIdx.x & 63;
    const int q = lane >> 4;
    const int l = lane & 15;
    const int node = blockIdx.x * 4 + wave;
    if (node >= N_NODES) return;

    const int off0 = offsets[node];
    const int off1 = offsets[node + 1];
    const uint2* pp = (const uint2*)p;   // row stride 16 uint2

    float a0 = 0.f, a1 = 0.f, a2 = 0.f, a3 = 0.f;
    int i = off0 + q;
    for (; i + 4 < off1; i += 8) {
        uint2 v0 = pp[(size_t)csr_src[i + 0] * 16 + l];
        uint2 v1 = pp[(size_t)csr_src[i + 4] * 16 + l];
        a0 += bf16lo(v0.x) + bf16lo(v1.x);
        a1 += bf16hi(v0.x) + bf16hi(v1.x);
        a2 += bf16lo(v0.y) + bf16lo(v1.y);
        a3 += bf16hi(v0.y) + bf16hi(v1.y);
    }
    for (; i < off1; i += 4) {
        uint2 v = pp[(size_t)csr_src[i] * 16 + l];
        a0 += bf16lo(v.x);
        a1 += bf16hi(v.x);
        a2 += bf16lo(v.y);
        a3 += bf16hi(v.y);
    }
    a0 += __shfl_xor(a0, 16); a0 += __shfl_xor(a0, 32);
    a1 += __shfl_xor(a1, 16); a1 += __shfl_xor(a1, 32);
    a2 += __shfl_xor(a2, 16); a2 += __shfl_xor(a2, 32);
    a3 += __shfl_xor(a3, 16); a3 += __shfl_xor(a3, 32);

    if (q == 0) {
        const float invdeg = 1.0f / fmaxf((float)(off1 - off0), 1.0f);
        float4 sv = ((float4*)out)[(size_t)node * 16 + l];
        sv.x += a0 * invdeg;
        sv.y += a1 * invdeg;
        sv.z += a2 * invdeg;
        sv.w += a3 * invdeg;
        ((float4*)out)[(size_t)node * 16 + l] = sv;
    }
}

extern "C" void kernel_launch(void* const* d_in, const int* in_sizes, int n_in,
                              void* d_out, int out_size, void* d_ws, size_t ws_size,
                              hipStream_t stream) {
    const float* x        = (const float*)d_in[0];
    const float* W_self1  = (const float*)d_in[1];
    const float* W_neigh1 = (const float*)d_in[2];
    const float* b1       = (const float*)d_in[3];
    const float* W_self2  = (const float*)d_in[4];
    const float* W_neigh2 = (const float*)d_in[5];
    const float* b2       = (const float*)d_in[6];
    const int*   src      = (const int*)d_in[7];
    const int*   dst      = (const int*)d_in[8];
    float* out = (float*)d_out;

    // workspace (4B units). Overlaps: h1b reuses xb (xb dead after gemm1);
    // p2 reuses p1 (p1 dead after agg1). Peak ~55 MB.
    int*   degi    = (int*)d_ws;                      // 50048
    int*   offsets = degi + 50048;                    // 50048
    int*   cursor  = offsets + 50048;                 // 50048
    int*   bsum    = cursor + 50048;                  // 64
    int*   bof     = bsum + 64;                       // 64
    int*   csr_src = bof + 64;                        // 800000
    unsigned short* Bp1 = (unsigned short*)(csr_src + 800000);          // 32768 bf16
    unsigned short* Bp2 = Bp1 + 32768;                                   // 16384 bf16
    unsigned short* xb  = Bp2 + 16384;                                   // 6.4M bf16 (-> h1b)
    unsigned short* h1b = xb;
    float* s1 = (float*)(xb + (size_t)N_NODES * 128);                    // 6.4M fp32
    unsigned short* p1 = (unsigned short*)(s1 + (size_t)N_NODES * 128);  // 6.4M bf16 (-> p2)
    unsigned short* p2 = p1;

    // ---- CSR build ----
    hipMemsetAsync(degi, 0, 50048 * sizeof(int), stream);
    hist_kernel<<<(N_EDGES + 255) / 256, 256, 0, stream>>>(dst, degi);
    scan1_kernel<<<SCAN_NBLK, 256, 0, stream>>>(degi, bsum);
    scan2_kernel<<<1, 64, 0, stream>>>(bsum, bof);
    scan3_kernel<<<SCAN_NBLK, 256, 0, stream>>>(degi, bof, offsets, cursor);
    fill_kernel<<<(N_EDGES + 255) / 256, 256, 0, stream>>>(src, dst, cursor, csr_src);

    // ---- prep: casts + weight packs ----
    cast_bf16_kernel<<<(N_NODES * 128 / 4 + 255) / 256, 256, 0, stream>>>(
        x, xb, N_NODES * 128 / 4);
    pack_w_kernel<256><<<(4 * 16 * 64 + 255) / 256, 256, 0, stream>>>(W_self1, W_neigh1, Bp1);
    pack_w_kernel<128><<<(4 * 8 * 64 + 255) / 256, 256, 0, stream>>>(W_self2, W_neigh2, Bp2);

    // ---- layer 1 ----
    gemm_mfma_kernel<256><<<(N_NODES + 31) / 32, 256, 0, stream>>>(xb, Bp1, b1, s1, p1);
    agg_relu_128_kernel<<<(N_NODES + 3) / 4, 256, 0, stream>>>(s1, p1, offsets, csr_src, h1b);

    // ---- layer 2 ----
    gemm_mfma_kernel<128><<<(N_NODES + 31) / 32, 256, 0, stream>>>(h1b, Bp2, b2, out, p2);
    agg_64_kernel<<<(N_NODES + 3) / 4, 256, 0, stream>>>(p2, offsets, csr_src, out);
}

// Round 6
// 263.009 us; speedup vs baseline: 4.2009x; 1.0553x over previous
//
#include <hip/hip_runtime.h>

#define N_NODES 50000
#define N_EDGES 800000
#define N_FEAT 128
#define N_HIDDEN 128
#define N_CLASSES 64

#define SCAN_CHUNK 1024
#define SCAN_NBLK ((N_NODES + SCAN_CHUNK - 1) / SCAN_CHUNK)  // 49

// block counts for fused kernels
#define CAST_BLK 6250                 // 50000*128/4 / 256
#define HIST_BLK 3125                 // 800000 / 256
#define PACK1_BLK 16                  // 4*16*64/256
#define PACK2_BLK 8                   // 4*8*64/256
#define PREP_BLK (CAST_BLK + HIST_BLK + PACK1_BLK + PACK2_BLK)
#define FILL_BLK 3125
#define GEMM1_BLK ((N_NODES + 31) / 32)   // 1563
#define FG_BLK (FILL_BLK + GEMM1_BLK)

typedef __attribute__((ext_vector_type(8))) short bf16x8;
typedef __attribute__((ext_vector_type(4))) float f32x4;

// ---------------- bf16 helpers (RNE pack, shift unpack) ----------------
__device__ __forceinline__ unsigned short f32_to_bf16(float f) {
    unsigned int u = __float_as_uint(f);
    return (unsigned short)((u + 0x7fffu + ((u >> 16) & 1u)) >> 16);
}
__device__ __forceinline__ float bf16lo(unsigned int v) { return __uint_as_float(v << 16); }
__device__ __forceinline__ float bf16hi(unsigned int v) { return __uint_as_float(v & 0xffff0000u); }

// ---------------------------------------------------------------------------
// Pack W helper (device): one thread per (t,c,lane) fragment dword-group
// ---------------------------------------------------------------------------
template <int NOUT>
__device__ void pack_w_body(int idx, const float* __restrict__ Wself,
                            const float* __restrict__ Wneigh,
                            unsigned short* __restrict__ Bp) {
    constexpr int NT = NOUT / 16;
    constexpr int NO = NOUT / 2;
    if (idx >= 4 * NT * 64) return;
    const int lane = idx & 63;
    const int tc = idx >> 6;
    const int c = tc % NT;
    const int t = tc / NT;
    const int n = c * 16 + (lane & 15);
    const int k0 = t * 32 + (lane >> 4) * 8;
    const float* W = (n < NO) ? Wself : Wneigh;
    const int nn = (n < NO) ? n : n - NO;
    ushort4 lo, hi;
    lo.x = f32_to_bf16(W[(k0 + 0) * NO + nn]);
    lo.y = f32_to_bf16(W[(k0 + 1) * NO + nn]);
    lo.z = f32_to_bf16(W[(k0 + 2) * NO + nn]);
    lo.w = f32_to_bf16(W[(k0 + 3) * NO + nn]);
    hi.x = f32_to_bf16(W[(k0 + 4) * NO + nn]);
    hi.y = f32_to_bf16(W[(k0 + 5) * NO + nn]);
    hi.z = f32_to_bf16(W[(k0 + 6) * NO + nn]);
    hi.w = f32_to_bf16(W[(k0 + 7) * NO + nn]);
    ((ushort4*)&Bp[(size_t)idx * 8])[0] = lo;
    ((ushort4*)&Bp[(size_t)idx * 8])[1] = hi;
}

// ---------------------------------------------------------------------------
// Fused prep: [cast x->bf16 | degree histogram | pack W1 | pack W2]
// ---------------------------------------------------------------------------
__global__ __launch_bounds__(256) void prep_kernel(
        const float* __restrict__ x, unsigned short* __restrict__ xb,
        const int* __restrict__ dst, int* __restrict__ degi,
        const float* __restrict__ Ws1, const float* __restrict__ Wn1,
        unsigned short* __restrict__ Bp1,
        const float* __restrict__ Ws2, const float* __restrict__ Wn2,
        unsigned short* __restrict__ Bp2) {
    const int b = blockIdx.x;
    const int t = threadIdx.x;
    if (b < CAST_BLK) {
        int i = b * 256 + t;                    // < 1.6M exactly
        float4 v = ((const float4*)x)[i];
        ushort4 o;
        o.x = f32_to_bf16(v.x);
        o.y = f32_to_bf16(v.y);
        o.z = f32_to_bf16(v.z);
        o.w = f32_to_bf16(v.w);
        ((ushort4*)xb)[i] = o;
    } else if (b < CAST_BLK + HIST_BLK) {
        int e = (b - CAST_BLK) * 256 + t;       // < 800000 exactly
        atomicAdd(&degi[dst[e]], 1);
    } else if (b < CAST_BLK + HIST_BLK + PACK1_BLK) {
        int idx = (b - CAST_BLK - HIST_BLK) * 256 + t;
        pack_w_body<256>(idx, Ws1, Wn1, Bp1);
    } else {
        int idx = (b - CAST_BLK - HIST_BLK - PACK1_BLK) * 256 + t;
        pack_w_body<128>(idx, Ws2, Wn2, Bp2);
    }
}

// ---------------------------------------------------------------------------
// Scan (3 tiny kernels)
// ---------------------------------------------------------------------------
__global__ __launch_bounds__(256) void scan1_kernel(const int* __restrict__ degi,
                                                    int* __restrict__ bsum) {
    __shared__ int red[256];
    const int t = threadIdx.x;
    const int base = blockIdx.x * SCAN_CHUNK + t * 4;
    int s = 0;
#pragma unroll
    for (int j = 0; j < 4; ++j) {
        int i = base + j;
        if (i < N_NODES) s += degi[i];
    }
    red[t] = s;
    __syncthreads();
    for (int st = 128; st > 0; st >>= 1) {
        if (t < st) red[t] += red[t + st];
        __syncthreads();
    }
    if (t == 0) bsum[blockIdx.x] = red[0];
}

__global__ void scan2_kernel(const int* __restrict__ bsum, int* __restrict__ bof) {
    const int t = threadIdx.x;  // 0..63
    int orig = (t < SCAN_NBLK) ? bsum[t] : 0;
    int v = orig;
    for (int s = 1; s < 64; s <<= 1) {
        int u = __shfl_up(v, s);
        if (t >= s) v += u;
    }
    if (t < SCAN_NBLK) bof[t] = v - orig;
}

__global__ __launch_bounds__(256) void scan3_kernel(const int* __restrict__ degi,
                                                    const int* __restrict__ bof,
                                                    int* __restrict__ offsets,
                                                    int* __restrict__ cursor) {
    __shared__ int part[256];
    const int t = threadIdx.x;
    const int base = blockIdx.x * SCAN_CHUNK + t * 4;

    int loc[4];
    int s = 0;
#pragma unroll
    for (int j = 0; j < 4; ++j) {
        int i = base + j;
        loc[j] = (i < N_NODES) ? degi[i] : 0;
        s += loc[j];
    }
    part[t] = s;
    __syncthreads();
    for (int st = 1; st < 256; st <<= 1) {
        int v = (t >= st) ? part[t - st] : 0;
        __syncthreads();
        part[t] += v;
        __syncthreads();
    }
    int run = bof[blockIdx.x] + part[t] - s;
#pragma unroll
    for (int j = 0; j < 4; ++j) {
        int i = base + j;
        if (i < N_NODES) {
            offsets[i] = run;
            cursor[i] = run;
            run += loc[j];
        }
    }
    if (blockIdx.x == 0 && t == 0) offsets[N_NODES] = N_EDGES;
}

// ---------------------------------------------------------------------------
// Fused: [CSR fill (ushort src) | layer-1 MFMA dual GEMM]
// ---------------------------------------------------------------------------
template <int NOUT>
__device__ void gemm_mfma_body(int gblk,
                               const unsigned short* __restrict__ xb,
                               const unsigned short* __restrict__ Bp,
                               const float* __restrict__ bias,
                               float* __restrict__ s,
                               unsigned short* __restrict__ p) {
    constexpr int NT = NOUT / 16;
    constexpr int NO = NOUT / 2;
    constexpr int NSUB = NT / 4;

    const int tid = threadIdx.x;
    const int wave = tid >> 6;
    const int lane = tid & 63;
    const int mcol = lane & 15;
    const int kgrp = lane >> 4;

    const int mbase = gblk * 32;
    int r0 = mbase + mcol;       if (r0 >= N_NODES) r0 = N_NODES - 1;
    int r1 = mbase + 16 + mcol;  if (r1 >= N_NODES) r1 = N_NODES - 1;

    f32x4 acc[2][NSUB];
#pragma unroll
    for (int mt = 0; mt < 2; ++mt)
#pragma unroll
        for (int c = 0; c < NSUB; ++c)
            acc[mt][c] = (f32x4){0.f, 0.f, 0.f, 0.f};

#pragma unroll
    for (int t = 0; t < 4; ++t) {
        bf16x8 a0 = *(const bf16x8*)&xb[(size_t)r0 * 128 + t * 32 + kgrp * 8];
        bf16x8 a1 = *(const bf16x8*)&xb[(size_t)r1 * 128 + t * 32 + kgrp * 8];
#pragma unroll
        for (int c = 0; c < NSUB; ++c) {
            const int ct = wave * NSUB + c;
            bf16x8 bfrag = *(const bf16x8*)&Bp[((size_t)(t * NT + ct) * 64 + lane) * 8];
            acc[0][c] = __builtin_amdgcn_mfma_f32_16x16x32_bf16(a0, bfrag, acc[0][c], 0, 0, 0);
            acc[1][c] = __builtin_amdgcn_mfma_f32_16x16x32_bf16(a1, bfrag, acc[1][c], 0, 0, 0);
        }
    }

    float bv[NSUB];
    int ncols[NSUB];
#pragma unroll
    for (int c = 0; c < NSUB; ++c) {
        ncols[c] = (wave * NSUB + c) * 16 + mcol;
        bv[c] = (ncols[c] < NO) ? bias[ncols[c]] : 0.f;
    }

#pragma unroll
    for (int mt = 0; mt < 2; ++mt) {
#pragma unroll
        for (int c = 0; c < NSUB; ++c) {
            const int ncol = ncols[c];
#pragma unroll
            for (int r = 0; r < 4; ++r) {
                const int node = mbase + mt * 16 + kgrp * 4 + r;
                if (node >= N_NODES) continue;
                const float v = acc[mt][c][r];
                if (ncol < NO) {
                    s[(size_t)node * NO + ncol] = v + bv[c];
                } else {
                    p[(size_t)node * NO + (ncol - NO)] = f32_to_bf16(v);
                }
            }
        }
    }
}

__global__ __launch_bounds__(256) void fill_gemm1_kernel(
        const int* __restrict__ src, const int* __restrict__ dst,
        int* __restrict__ cursor, unsigned short* __restrict__ csr16,
        const unsigned short* __restrict__ xb,
        const unsigned short* __restrict__ Bp1,
        const float* __restrict__ b1,
        float* __restrict__ s1, unsigned short* __restrict__ p1) {
    const int b = blockIdx.x;
    if (b < FILL_BLK) {
        int e = b * 256 + threadIdx.x;          // < 800000 exactly
        int d = dst[e];
        int sr = src[e];
        int pos = atomicAdd(&cursor[d], 1);
        csr16[pos] = (unsigned short)sr;
    } else {
        gemm_mfma_body<256>(b - FILL_BLK, xb, Bp1, b1, s1, p1);
    }
}

__global__ __launch_bounds__(256) void gemm2_kernel(
        const unsigned short* __restrict__ h1b,
        const unsigned short* __restrict__ Bp2,
        const float* __restrict__ b2,
        float* __restrict__ s2, unsigned short* __restrict__ p2) {
    gemm_mfma_body<128>(blockIdx.x, h1b, Bp2, b2, s2, p2);
}

// ---------------------------------------------------------------------------
// Aggregate, F=128: wave/node, half-wave/stream, 8 neighbors in flight/stream.
// h1b = relu(s + mean gather(p))  (bf16 out)
// ---------------------------------------------------------------------------
__global__ __launch_bounds__(256) void agg_relu_128_kernel(
        const float* __restrict__ s,
        const unsigned short* __restrict__ p,
        const int* __restrict__ offsets,
        const unsigned short* __restrict__ csr16,
        unsigned short* __restrict__ h1b) {
    const int wave = threadIdx.x >> 6;
    const int lane = threadIdx.x & 63;
    const int half = lane >> 5;
    const int l = lane & 31;
    const int node = blockIdx.x * 4 + wave;
    if (node >= N_NODES) return;

    const int off0 = offsets[node];
    const int off1 = offsets[node + 1];
    const uint2* pp = (const uint2*)p;   // row stride 32 uint2

    float a0 = 0.f, a1 = 0.f, a2 = 0.f, a3 = 0.f;
    int i = off0 + half;
    for (; i + 14 < off1; i += 16) {   // 8 neighbors per half-stream per iter
        uint2 v0 = pp[(size_t)csr16[i + 0] * 32 + l];
        uint2 v1 = pp[(size_t)csr16[i + 2] * 32 + l];
        uint2 v2 = pp[(size_t)csr16[i + 4] * 32 + l];
        uint2 v3 = pp[(size_t)csr16[i + 6] * 32 + l];
        uint2 v4 = pp[(size_t)csr16[i + 8] * 32 + l];
        uint2 v5 = pp[(size_t)csr16[i + 10] * 32 + l];
        uint2 v6 = pp[(size_t)csr16[i + 12] * 32 + l];
        uint2 v7 = pp[(size_t)csr16[i + 14] * 32 + l];
        a0 += bf16lo(v0.x) + bf16lo(v1.x) + bf16lo(v2.x) + bf16lo(v3.x)
            + bf16lo(v4.x) + bf16lo(v5.x) + bf16lo(v6.x) + bf16lo(v7.x);
        a1 += bf16hi(v0.x) + bf16hi(v1.x) + bf16hi(v2.x) + bf16hi(v3.x)
            + bf16hi(v4.x) + bf16hi(v5.x) + bf16hi(v6.x) + bf16hi(v7.x);
        a2 += bf16lo(v0.y) + bf16lo(v1.y) + bf16lo(v2.y) + bf16lo(v3.y)
            + bf16lo(v4.y) + bf16lo(v5.y) + bf16lo(v6.y) + bf16lo(v7.y);
        a3 += bf16hi(v0.y) + bf16hi(v1.y) + bf16hi(v2.y) + bf16hi(v3.y)
            + bf16hi(v4.y) + bf16hi(v5.y) + bf16hi(v6.y) + bf16hi(v7.y);
    }
    for (; i < off1; i += 2) {
        uint2 v = pp[(size_t)csr16[i] * 32 + l];
        a0 += bf16lo(v.x);
        a1 += bf16hi(v.x);
        a2 += bf16lo(v.y);
        a3 += bf16hi(v.y);
    }
    a0 += __shfl_xor(a0, 32);
    a1 += __shfl_xor(a1, 32);
    a2 += __shfl_xor(a2, 32);
    a3 += __shfl_xor(a3, 32);

    if (half == 0) {
        const float invdeg = 1.0f / fmaxf((float)(off1 - off0), 1.0f);
        float4 sv = ((const float4*)s)[(size_t)node * 32 + l];
        ushort4 o;
        o.x = f32_to_bf16(fmaxf(sv.x + a0 * invdeg, 0.f));
        o.y = f32_to_bf16(fmaxf(sv.y + a1 * invdeg, 0.f));
        o.z = f32_to_bf16(fmaxf(sv.z + a2 * invdeg, 0.f));
        o.w = f32_to_bf16(fmaxf(sv.w + a3 * invdeg, 0.f));
        ((ushort4*)h1b)[(size_t)node * 32 + l] = o;
    }
}

// ---------------------------------------------------------------------------
// Aggregate, F=64: wave/node, quarter-wave/stream, 4 neighbors in flight/stream.
// out += mean gather(p)  (fp32 in place)
// ---------------------------------------------------------------------------
__global__ __launch_bounds__(256) void agg_64_kernel(
        const unsigned short* __restrict__ p,
        const int* __restrict__ offsets,
        const unsigned short* __restrict__ csr16,
        float* __restrict__ out) {
    const int wave = threadIdx.x >> 6;
    const int lane = threadIdx.x & 63;
    const int q = lane >> 4;
    const int l = lane & 15;
    const int node = blockIdx.x * 4 + wave;
    if (node >= N_NODES) return;

    const int off0 = offsets[node];
    const int off1 = offsets[node + 1];
    const uint2* pp = (const uint2*)p;   // row stride 16 uint2

    float a0 = 0.f, a1 = 0.f, a2 = 0.f, a3 = 0.f;
    int i = off0 + q;
    for (; i + 12 < off1; i += 16) {   // 4 neighbors per quarter-stream per iter
        uint2 v0 = pp[(size_t)csr16[i + 0] * 16 + l];
        uint2 v1 = pp[(size_t)csr16[i + 4] * 16 + l];
        uint2 v2 = pp[(size_t)csr16[i + 8] * 16 + l];
        uint2 v3 = pp[(size_t)csr16[i + 12] * 16 + l];
        a0 += bf16lo(v0.x) + bf16lo(v1.x) + bf16lo(v2.x) + bf16lo(v3.x);
        a1 += bf16hi(v0.x) + bf16hi(v1.x) + bf16hi(v2.x) + bf16hi(v3.x);
        a2 += bf16lo(v0.y) + bf16lo(v1.y) + bf16lo(v2.y) + bf16lo(v3.y);
        a3 += bf16hi(v0.y) + bf16hi(v1.y) + bf16hi(v2.y) + bf16hi(v3.y);
    }
    for (; i < off1; i += 4) {
        uint2 v = pp[(size_t)csr16[i] * 16 + l];
        a0 += bf16lo(v.x);
        a1 += bf16hi(v.x);
        a2 += bf16lo(v.y);
        a3 += bf16hi(v.y);
    }
    a0 += __shfl_xor(a0, 16); a0 += __shfl_xor(a0, 32);
    a1 += __shfl_xor(a1, 16); a1 += __shfl_xor(a1, 32);
    a2 += __shfl_xor(a2, 16); a2 += __shfl_xor(a2, 32);
    a3 += __shfl_xor(a3, 16); a3 += __shfl_xor(a3, 32);

    if (q == 0) {
        const float invdeg = 1.0f / fmaxf((float)(off1 - off0), 1.0f);
        float4 sv = ((float4*)out)[(size_t)node * 16 + l];
        sv.x += a0 * invdeg;
        sv.y += a1 * invdeg;
        sv.z += a2 * invdeg;
        sv.w += a3 * invdeg;
        ((float4*)out)[(size_t)node * 16 + l] = sv;
    }
}

extern "C" void kernel_launch(void* const* d_in, const int* in_sizes, int n_in,
                              void* d_out, int out_size, void* d_ws, size_t ws_size,
                              hipStream_t stream) {
    const float* x        = (const float*)d_in[0];
    const float* W_self1  = (const float*)d_in[1];
    const float* W_neigh1 = (const float*)d_in[2];
    const float* b1       = (const float*)d_in[3];
    const float* W_self2  = (const float*)d_in[4];
    const float* W_neigh2 = (const float*)d_in[5];
    const float* b2       = (const float*)d_in[6];
    const int*   src      = (const int*)d_in[7];
    const int*   dst      = (const int*)d_in[8];
    float* out = (float*)d_out;

    // workspace (4B units). Overlaps: h1b reuses xb; p2 reuses p1.
    int*   degi    = (int*)d_ws;                      // 50048
    int*   offsets = degi + 50048;                    // 50048
    int*   cursor  = offsets + 50048;                 // 50048
    int*   bsum    = cursor + 50048;                  // 64
    int*   bof     = bsum + 64;                       // 64
    unsigned short* csr16 = (unsigned short*)(bof + 64);                 // 800000 ushort
    unsigned short* Bp1 = csr16 + 800000;                                 // 32768 bf16
    unsigned short* Bp2 = Bp1 + 32768;                                    // 16384 bf16
    unsigned short* xb  = Bp2 + 16384;                                    // 6.4M bf16 (-> h1b)
    unsigned short* h1b = xb;
    float* s1 = (float*)(xb + (size_t)N_NODES * 128);                     // 6.4M fp32
    unsigned short* p1 = (unsigned short*)(s1 + (size_t)N_NODES * 128);   // 6.4M bf16 (-> p2)
    unsigned short* p2 = p1;

    // ---- prep (cast | hist | packs) ----
    hipMemsetAsync(degi, 0, 50048 * sizeof(int), stream);
    prep_kernel<<<PREP_BLK, 256, 0, stream>>>(x, xb, dst, degi,
                                              W_self1, W_neigh1, Bp1,
                                              W_self2, W_neigh2, Bp2);

    // ---- scan ----
    scan1_kernel<<<SCAN_NBLK, 256, 0, stream>>>(degi, bsum);
    scan2_kernel<<<1, 64, 0, stream>>>(bsum, bof);
    scan3_kernel<<<SCAN_NBLK, 256, 0, stream>>>(degi, bof, offsets, cursor);

    // ---- fill + layer-1 GEMM (fused) ----
    fill_gemm1_kernel<<<FG_BLK, 256, 0, stream>>>(src, dst, cursor, csr16,
                                                  xb, Bp1, b1, s1, p1);

    // ---- layer-1 aggregate ----
    agg_relu_128_kernel<<<(N_NODES + 3) / 4, 256, 0, stream>>>(s1, p1, offsets, csr16, h1b);

    // ---- layer 2 ----
    gemm2_kernel<<<(N_NODES + 31) / 32, 256, 0, stream>>>(h1b, Bp2, b2, out, p2);
    agg_64_kernel<<<(N_NODES + 3) / 4, 256, 0, stream>>>(p2, offsets, csr16, out);
}

// Round 7
// 231.996 us; speedup vs baseline: 4.7625x; 1.1337x over previous
//
#include <hip/hip_runtime.h>

#define N_NODES 50000
#define N_EDGES 800000
#define N_FEAT 128
#define N_HIDDEN 128
#define N_CLASSES 64

#define NBUCK 256
#define BUCK_NODES 196        // ceil(50000/256); 256*196 = 50176 >= 50000
#define BIN_CHUNK 8192
#define BIN_BLK ((N_EDGES + BIN_CHUNK - 1) / BIN_CHUNK)   // 98

// block counts for fused kernels
#define CAST_BLK 6250                 // 50000*128/4 / 256
#define PACK1_BLK 16                  // 4*16*64/256
#define PACK2_BLK 8                   // 4*8*64/256
#define PREP_BLK (CAST_BLK + BIN_BLK + PACK1_BLK + PACK2_BLK)
#define GEMM1_BLK ((N_NODES + 31) / 32)   // 1563
#define BG_BLK (BIN_BLK + GEMM1_BLK)

typedef __attribute__((ext_vector_type(8))) short bf16x8;
typedef __attribute__((ext_vector_type(4))) float f32x4;

// ---------------- bf16 helpers (RNE pack, shift unpack) ----------------
__device__ __forceinline__ unsigned short f32_to_bf16(float f) {
    unsigned int u = __float_as_uint(f);
    return (unsigned short)((u + 0x7fffu + ((u >> 16) & 1u)) >> 16);
}
__device__ __forceinline__ float bf16lo(unsigned int v) { return __uint_as_float(v << 16); }
__device__ __forceinline__ float bf16hi(unsigned int v) { return __uint_as_float(v & 0xffff0000u); }

// ---------------------------------------------------------------------------
// Pack W helper (device)
// ---------------------------------------------------------------------------
template <int NOUT>
__device__ void pack_w_body(int idx, const float* __restrict__ Wself,
                            const float* __restrict__ Wneigh,
                            unsigned short* __restrict__ Bp) {
    constexpr int NT = NOUT / 16;
    constexpr int NO = NOUT / 2;
    if (idx >= 4 * NT * 64) return;
    const int lane = idx & 63;
    const int tc = idx >> 6;
    const int c = tc % NT;
    const int t = tc / NT;
    const int n = c * 16 + (lane & 15);
    const int k0 = t * 32 + (lane >> 4) * 8;
    const float* W = (n < NO) ? Wself : Wneigh;
    const int nn = (n < NO) ? n : n - NO;
    ushort4 lo, hi;
    lo.x = f32_to_bf16(W[(k0 + 0) * NO + nn]);
    lo.y = f32_to_bf16(W[(k0 + 1) * NO + nn]);
    lo.z = f32_to_bf16(W[(k0 + 2) * NO + nn]);
    lo.w = f32_to_bf16(W[(k0 + 3) * NO + nn]);
    hi.x = f32_to_bf16(W[(k0 + 4) * NO + nn]);
    hi.y = f32_to_bf16(W[(k0 + 5) * NO + nn]);
    hi.z = f32_to_bf16(W[(k0 + 6) * NO + nn]);
    hi.w = f32_to_bf16(W[(k0 + 7) * NO + nn]);
    ((ushort4*)&Bp[(size_t)idx * 8])[0] = lo;
    ((ushort4*)&Bp[(size_t)idx * 8])[1] = hi;
}

// ---------------------------------------------------------------------------
// Pass A0 body: per-block LDS bucket histogram of dst/196
// ---------------------------------------------------------------------------
__device__ void a0_body(int blk, const int* __restrict__ dst, int* __restrict__ bcount) {
    __shared__ int h[NBUCK];
    const int t = threadIdx.x;
    h[t] = 0;
    __syncthreads();
    const int lo = blk * BIN_CHUNK;
    const int hi = min(lo + BIN_CHUNK, N_EDGES);
    for (int i = lo + t; i < hi; i += 256) {
        atomicAdd(&h[dst[i] / BUCK_NODES], 1);
    }
    __syncthreads();
    if (h[t] > 0) atomicAdd(&bcount[t], h[t]);
}

// ---------------------------------------------------------------------------
// Fused prep: [cast x->bf16 | bucket histogram (A0) | pack W1 | pack W2]
// ---------------------------------------------------------------------------
__global__ __launch_bounds__(256) void prep_kernel(
        const float* __restrict__ x, unsigned short* __restrict__ xb,
        const int* __restrict__ dst, int* __restrict__ bcount,
        const float* __restrict__ Ws1, const float* __restrict__ Wn1,
        unsigned short* __restrict__ Bp1,
        const float* __restrict__ Ws2, const float* __restrict__ Wn2,
        unsigned short* __restrict__ Bp2) {
    const int b = blockIdx.x;
    const int t = threadIdx.x;
    if (b < CAST_BLK) {
        int i = b * 256 + t;                    // < 1.6M exactly
        float4 v = ((const float4*)x)[i];
        ushort4 o;
        o.x = f32_to_bf16(v.x);
        o.y = f32_to_bf16(v.y);
        o.z = f32_to_bf16(v.z);
        o.w = f32_to_bf16(v.w);
        ((ushort4*)xb)[i] = o;
    } else if (b < CAST_BLK + BIN_BLK) {
        a0_body(b - CAST_BLK, dst, bcount);
    } else if (b < CAST_BLK + BIN_BLK + PACK1_BLK) {
        int idx = (b - CAST_BLK - BIN_BLK) * 256 + t;
        pack_w_body<256>(idx, Ws1, Wn1, Bp1);
    } else {
        int idx = (b - CAST_BLK - BIN_BLK - PACK1_BLK) * 256 + t;
        pack_w_body<128>(idx, Ws2, Wn2, Bp2);
    }
}

// ---------------------------------------------------------------------------
// Bucket scan: exclusive scan of 256 bucket counts -> bstart[257], bcursor
// ---------------------------------------------------------------------------
__global__ __launch_bounds__(256) void bscan_kernel(const int* __restrict__ bcount,
                                                    int* __restrict__ bstart,
                                                    int* __restrict__ bcursor) {
    __shared__ int sc[NBUCK];
    const int t = threadIdx.x;
    const int v = bcount[t];
    sc[t] = v;
    __syncthreads();
    for (int s = 1; s < NBUCK; s <<= 1) {
        int u = (t >= s) ? sc[t - s] : 0;
        __syncthreads();
        sc[t] += u;
        __syncthreads();
    }
    const int excl = sc[t] - v;
    bstart[t] = excl;
    bcursor[t] = excl;
    if (t == NBUCK - 1) bstart[NBUCK] = sc[t];   // == N_EDGES
}

// ---------------------------------------------------------------------------
// Pass A1 body: bin edges into bucket regions as (dst_local<<16 | src)
// ---------------------------------------------------------------------------
__device__ void a1_body(int blk, const int* __restrict__ src, const int* __restrict__ dst,
                        int* __restrict__ bcursor, unsigned int* __restrict__ binned) {
    __shared__ int h[NBUCK];
    __shared__ int base[NBUCK];
    const int t = threadIdx.x;
    h[t] = 0;
    __syncthreads();
    const int lo = blk * BIN_CHUNK;
    const int hi = min(lo + BIN_CHUNK, N_EDGES);
    for (int i = lo + t; i < hi; i += 256) {
        atomicAdd(&h[dst[i] / BUCK_NODES], 1);
    }
    __syncthreads();
    if (h[t] > 0) base[t] = atomicAdd(&bcursor[t], h[t]);
    h[t] = 0;
    __syncthreads();
    for (int i = lo + t; i < hi; i += 256) {
        const int d = dst[i];
        const int b = d / BUCK_NODES;
        const int r = atomicAdd(&h[b], 1);
        binned[base[b] + r] = ((unsigned int)(d - b * BUCK_NODES) << 16) | (unsigned int)src[i];
    }
}

// ---------------------------------------------------------------------------
// MFMA dual GEMM body (unchanged, verified R5/R6)
// ---------------------------------------------------------------------------
template <int NOUT>
__device__ void gemm_mfma_body(int gblk,
                               const unsigned short* __restrict__ xb,
                               const unsigned short* __restrict__ Bp,
                               const float* __restrict__ bias,
                               float* __restrict__ s,
                               unsigned short* __restrict__ p) {
    constexpr int NT = NOUT / 16;
    constexpr int NO = NOUT / 2;
    constexpr int NSUB = NT / 4;

    const int tid = threadIdx.x;
    const int wave = tid >> 6;
    const int lane = tid & 63;
    const int mcol = lane & 15;
    const int kgrp = lane >> 4;

    const int mbase = gblk * 32;
    int r0 = mbase + mcol;       if (r0 >= N_NODES) r0 = N_NODES - 1;
    int r1 = mbase + 16 + mcol;  if (r1 >= N_NODES) r1 = N_NODES - 1;

    f32x4 acc[2][NSUB];
#pragma unroll
    for (int mt = 0; mt < 2; ++mt)
#pragma unroll
        for (int c = 0; c < NSUB; ++c)
            acc[mt][c] = (f32x4){0.f, 0.f, 0.f, 0.f};

#pragma unroll
    for (int t = 0; t < 4; ++t) {
        bf16x8 a0 = *(const bf16x8*)&xb[(size_t)r0 * 128 + t * 32 + kgrp * 8];
        bf16x8 a1 = *(const bf16x8*)&xb[(size_t)r1 * 128 + t * 32 + kgrp * 8];
#pragma unroll
        for (int c = 0; c < NSUB; ++c) {
            const int ct = wave * NSUB + c;
            bf16x8 bfrag = *(const bf16x8*)&Bp[((size_t)(t * NT + ct) * 64 + lane) * 8];
            acc[0][c] = __builtin_amdgcn_mfma_f32_16x16x32_bf16(a0, bfrag, acc[0][c], 0, 0, 0);
            acc[1][c] = __builtin_amdgcn_mfma_f32_16x16x32_bf16(a1, bfrag, acc[1][c], 0, 0, 0);
        }
    }

    float bv[NSUB];
    int ncols[NSUB];
#pragma unroll
    for (int c = 0; c < NSUB; ++c) {
        ncols[c] = (wave * NSUB + c) * 16 + mcol;
        bv[c] = (ncols[c] < NO) ? bias[ncols[c]] : 0.f;
    }

#pragma unroll
    for (int mt = 0; mt < 2; ++mt) {
#pragma unroll
        for (int c = 0; c < NSUB; ++c) {
            const int ncol = ncols[c];
#pragma unroll
            for (int r = 0; r < 4; ++r) {
                const int node = mbase + mt * 16 + kgrp * 4 + r;
                if (node >= N_NODES) continue;
                const float v = acc[mt][c][r];
                if (ncol < NO) {
                    s[(size_t)node * NO + ncol] = v + bv[c];
                } else {
                    p[(size_t)node * NO + (ncol - NO)] = f32_to_bf16(v);
                }
            }
        }
    }
}

// ---------------------------------------------------------------------------
// Fused: [bin pass A1 | layer-1 MFMA dual GEMM]
// ---------------------------------------------------------------------------
__global__ __launch_bounds__(256) void bin_gemm1_kernel(
        const int* __restrict__ src, const int* __restrict__ dst,
        int* __restrict__ bcursor, unsigned int* __restrict__ binned,
        const unsigned short* __restrict__ xb,
        const unsigned short* __restrict__ Bp1,
        const float* __restrict__ b1,
        float* __restrict__ s1, unsigned short* __restrict__ p1) {
    const int b = blockIdx.x;
    if (b < BIN_BLK) {
        a1_body(b, src, dst, bcursor, binned);
    } else {
        gemm_mfma_body<256>(b - BIN_BLK, xb, Bp1, b1, s1, p1);
    }
}

// ---------------------------------------------------------------------------
// Pass B: one block per bucket. Local counting sort -> csr16 + offsets.
// Bucket region is ~6.25 KB (L2-resident during the block) -> coalesced WB.
// ---------------------------------------------------------------------------
__global__ __launch_bounds__(256) void bucket_build_kernel(
        const unsigned int* __restrict__ binned,
        const int* __restrict__ bstart,
        int* __restrict__ offsets,
        unsigned short* __restrict__ csr16) {
    __shared__ int cnt[NBUCK];
    __shared__ int pre[NBUCK];
    const int b = blockIdx.x;
    const int t = threadIdx.x;
    const int n0 = b * BUCK_NODES;
    const int nn = min(N_NODES - n0, BUCK_NODES);   // nodes in this bucket
    const int e0 = bstart[b];
    const int e1 = bstart[b + 1];

    cnt[t] = 0;
    __syncthreads();
    for (int i = e0 + t; i < e1; i += 256) {
        atomicAdd(&cnt[binned[i] >> 16], 1);
    }
    __syncthreads();
    // exclusive scan over 256 (only first nn nonzero)
    int v = cnt[t];
    pre[t] = v;
    __syncthreads();
    for (int s = 1; s < NBUCK; s <<= 1) {
        int u = (t >= s) ? pre[t - s] : 0;
        __syncthreads();
        pre[t] += u;
        __syncthreads();
    }
    const int excl = pre[t] - v;
    if (t < nn) offsets[n0 + t] = e0 + excl;
    if (b == 0 && t == 0) offsets[N_NODES] = N_EDGES;
    __syncthreads();
    pre[t] = excl;
    cnt[t] = 0;
    __syncthreads();
    for (int i = e0 + t; i < e1; i += 256) {
        const unsigned int u = binned[i];
        const int dl = (int)(u >> 16);
        const int r = atomicAdd(&cnt[dl], 1);
        csr16[e0 + pre[dl] + r] = (unsigned short)(u & 0xffffu);
    }
}

__global__ __launch_bounds__(256) void gemm2_kernel(
        const unsigned short* __restrict__ h1b,
        const unsigned short* __restrict__ Bp2,
        const float* __restrict__ b2,
        float* __restrict__ s2, unsigned short* __restrict__ p2) {
    gemm_mfma_body<128>(blockIdx.x, h1b, Bp2, b2, s2, p2);
}

// ---------------------------------------------------------------------------
// Aggregate, F=128 (unchanged, verified R6)
// ---------------------------------------------------------------------------
__global__ __launch_bounds__(256) void agg_relu_128_kernel(
        const float* __restrict__ s,
        const unsigned short* __restrict__ p,
        const int* __restrict__ offsets,
        const unsigned short* __restrict__ csr16,
        unsigned short* __restrict__ h1b) {
    const int wave = threadIdx.x >> 6;
    const int lane = threadIdx.x & 63;
    const int half = lane >> 5;
    const int l = lane & 31;
    const int node = blockIdx.x * 4 + wave;
    if (node >= N_NODES) return;

    const int off0 = offsets[node];
    const int off1 = offsets[node + 1];
    const uint2* pp = (const uint2*)p;   // row stride 32 uint2

    float a0 = 0.f, a1 = 0.f, a2 = 0.f, a3 = 0.f;
    int i = off0 + half;
    for (; i + 14 < off1; i += 16) {
        uint2 v0 = pp[(size_t)csr16[i + 0] * 32 + l];
        uint2 v1 = pp[(size_t)csr16[i + 2] * 32 + l];
        uint2 v2 = pp[(size_t)csr16[i + 4] * 32 + l];
        uint2 v3 = pp[(size_t)csr16[i + 6] * 32 + l];
        uint2 v4 = pp[(size_t)csr16[i + 8] * 32 + l];
        uint2 v5 = pp[(size_t)csr16[i + 10] * 32 + l];
        uint2 v6 = pp[(size_t)csr16[i + 12] * 32 + l];
        uint2 v7 = pp[(size_t)csr16[i + 14] * 32 + l];
        a0 += bf16lo(v0.x) + bf16lo(v1.x) + bf16lo(v2.x) + bf16lo(v3.x)
            + bf16lo(v4.x) + bf16lo(v5.x) + bf16lo(v6.x) + bf16lo(v7.x);
        a1 += bf16hi(v0.x) + bf16hi(v1.x) + bf16hi(v2.x) + bf16hi(v3.x)
            + bf16hi(v4.x) + bf16hi(v5.x) + bf16hi(v6.x) + bf16hi(v7.x);
        a2 += bf16lo(v0.y) + bf16lo(v1.y) + bf16lo(v2.y) + bf16lo(v3.y)
            + bf16lo(v4.y) + bf16lo(v5.y) + bf16lo(v6.y) + bf16lo(v7.y);
        a3 += bf16hi(v0.y) + bf16hi(v1.y) + bf16hi(v2.y) + bf16hi(v3.y)
            + bf16hi(v4.y) + bf16hi(v5.y) + bf16hi(v6.y) + bf16hi(v7.y);
    }
    for (; i < off1; i += 2) {
        uint2 v = pp[(size_t)csr16[i] * 32 + l];
        a0 += bf16lo(v.x);
        a1 += bf16hi(v.x);
        a2 += bf16lo(v.y);
        a3 += bf16hi(v.y);
    }
    a0 += __shfl_xor(a0, 32);
    a1 += __shfl_xor(a1, 32);
    a2 += __shfl_xor(a2, 32);
    a3 += __shfl_xor(a3, 32);

    if (half == 0) {
        const float invdeg = 1.0f / fmaxf((float)(off1 - off0), 1.0f);
        float4 sv = ((const float4*)s)[(size_t)node * 32 + l];
        ushort4 o;
        o.x = f32_to_bf16(fmaxf(sv.x + a0 * invdeg, 0.f));
        o.y = f32_to_bf16(fmaxf(sv.y + a1 * invdeg, 0.f));
        o.z = f32_to_bf16(fmaxf(sv.z + a2 * invdeg, 0.f));
        o.w = f32_to_bf16(fmaxf(sv.w + a3 * invdeg, 0.f));
        ((ushort4*)h1b)[(size_t)node * 32 + l] = o;
    }
}

// ---------------------------------------------------------------------------
// Aggregate, F=64 (unchanged, verified R6)
// ---------------------------------------------------------------------------
__global__ __launch_bounds__(256) void agg_64_kernel(
        const unsigned short* __restrict__ p,
        const int* __restrict__ offsets,
        const unsigned short* __restrict__ csr16,
        float* __restrict__ out) {
    const int wave = threadIdx.x >> 6;
    const int lane = threadIdx.x & 63;
    const int q = lane >> 4;
    const int l = lane & 15;
    const int node = blockIdx.x * 4 + wave;
    if (node >= N_NODES) return;

    const int off0 = offsets[node];
    const int off1 = offsets[node + 1];
    const uint2* pp = (const uint2*)p;   // row stride 16 uint2

    float a0 = 0.f, a1 = 0.f, a2 = 0.f, a3 = 0.f;
    int i = off0 + q;
    for (; i + 12 < off1; i += 16) {
        uint2 v0 = pp[(size_t)csr16[i + 0] * 16 + l];
        uint2 v1 = pp[(size_t)csr16[i + 4] * 16 + l];
        uint2 v2 = pp[(size_t)csr16[i + 8] * 16 + l];
        uint2 v3 = pp[(size_t)csr16[i + 12] * 16 + l];
        a0 += bf16lo(v0.x) + bf16lo(v1.x) + bf16lo(v2.x) + bf16lo(v3.x);
        a1 += bf16hi(v0.x) + bf16hi(v1.x) + bf16hi(v2.x) + bf16hi(v3.x);
        a2 += bf16lo(v0.y) + bf16lo(v1.y) + bf16lo(v2.y) + bf16lo(v3.y);
        a3 += bf16hi(v0.y) + bf16hi(v1.y) + bf16hi(v2.y) + bf16hi(v3.y);
    }
    for (; i < off1; i += 4) {
        uint2 v = pp[(size_t)csr16[i] * 16 + l];
        a0 += bf16lo(v.x);
        a1 += bf16hi(v.x);
        a2 += bf16lo(v.y);
        a3 += bf16hi(v.y);
    }
    a0 += __shfl_xor(a0, 16); a0 += __shfl_xor(a0, 32);
    a1 += __shfl_xor(a1, 16); a1 += __shfl_xor(a1, 32);
    a2 += __shfl_xor(a2, 16); a2 += __shfl_xor(a2, 32);
    a3 += __shfl_xor(a3, 16); a3 += __shfl_xor(a3, 32);

    if (q == 0) {
        const float invdeg = 1.0f / fmaxf((float)(off1 - off0), 1.0f);
        float4 sv = ((float4*)out)[(size_t)node * 16 + l];
        sv.x += a0 * invdeg;
        sv.y += a1 * invdeg;
        sv.z += a2 * invdeg;
        sv.w += a3 * invdeg;
        ((float4*)out)[(size_t)node * 16 + l] = sv;
    }
}

extern "C" void kernel_launch(void* const* d_in, const int* in_sizes, int n_in,
                              void* d_out, int out_size, void* d_ws, size_t ws_size,
                              hipStream_t stream) {
    const float* x        = (const float*)d_in[0];
    const float* W_self1  = (const float*)d_in[1];
    const float* W_neigh1 = (const float*)d_in[2];
    const float* b1       = (const float*)d_in[3];
    const float* W_self2  = (const float*)d_in[4];
    const float* W_neigh2 = (const float*)d_in[5];
    const float* b2       = (const float*)d_in[6];
    const int*   src      = (const int*)d_in[7];
    const int*   dst      = (const int*)d_in[8];
    float* out = (float*)d_out;

    // workspace (4B units). Overlaps: h1b reuses xb; p2 reuses p1. ~56 MB.
    int* bcount  = (int*)d_ws;                        // 256
    int* bstart  = bcount + 256;                      // 288 (uses 257)
    int* bcursor = bstart + 288;                      // 256
    int* offsets = bcursor + 256;                     // 50048 (uses 50001)
    unsigned int* binned = (unsigned int*)(offsets + 50048);              // 800000 uint
    unsigned short* csr16 = (unsigned short*)(binned + 800000);           // 800000 ushort
    unsigned short* Bp1 = csr16 + 800000;                                  // 32768 bf16
    unsigned short* Bp2 = Bp1 + 32768;                                     // 16384 bf16
    unsigned short* xb  = Bp2 + 16384;                                     // 6.4M bf16 (-> h1b)
    unsigned short* h1b = xb;
    float* s1 = (float*)(xb + (size_t)N_NODES * 128);                      // 6.4M fp32
    unsigned short* p1 = (unsigned short*)(s1 + (size_t)N_NODES * 128);    // 6.4M bf16 (-> p2)
    unsigned short* p2 = p1;

    // ---- prep (cast | bucket hist | packs) ----
    hipMemsetAsync(bcount, 0, 256 * sizeof(int), stream);
    prep_kernel<<<PREP_BLK, 256, 0, stream>>>(x, xb, dst, bcount,
                                              W_self1, W_neigh1, Bp1,
                                              W_self2, W_neigh2, Bp2);

    // ---- bucket scan ----
    bscan_kernel<<<1, 256, 0, stream>>>(bcount, bstart, bcursor);

    // ---- bin (A1) + layer-1 GEMM (fused) ----
    bin_gemm1_kernel<<<BG_BLK, 256, 0, stream>>>(src, dst, bcursor, binned,
                                                 xb, Bp1, b1, s1, p1);

    // ---- per-bucket CSR build (B) ----
    bucket_build_kernel<<<NBUCK, 256, 0, stream>>>(binned, bstart, offsets, csr16);

    // ---- layer-1 aggregate ----
    agg_relu_128_kernel<<<(N_NODES + 3) / 4, 256, 0, stream>>>(s1, p1, offsets, csr16, h1b);

    // ---- layer 2 ----
    gemm2_kernel<<<(N_NODES + 31) / 32, 256, 0, stream>>>(h1b, Bp2, b2, out, p2);
    agg_64_kernel<<<(N_NODES + 3) / 4, 256, 0, stream>>>(p2, offsets, csr16, out);
}

// Round 8
// 209.732 us; speedup vs baseline: 5.2681x; 1.1062x over previous
//
#include <hip/hip_runtime.h>

#define N_NODES 50000
#define N_EDGES 800000
#define N_FEAT 128
#define N_HIDDEN 128
#define N_CLASSES 64

#define NBUCK 256
#define BUCK_NODES 196        // ceil(50000/256)
#define A0_CHUNK 8192
#define A0_BLK ((N_EDGES + A0_CHUNK - 1) / A0_CHUNK)      // 98
#define BIN_CHUNK 2048
#define BIN_BLK ((N_EDGES + BIN_CHUNK - 1) / BIN_CHUNK)   // 391

#define CAST_BLK 6250
#define PACK1_BLK 16
#define PACK2_BLK 8
#define PREP_BLK (CAST_BLK + A0_BLK + PACK1_BLK + PACK2_BLK)
#define GEMM1_BLK ((N_NODES + 31) / 32)   // 1563
#define BG_BLK (BIN_BLK + GEMM1_BLK)

typedef __attribute__((ext_vector_type(8))) short bf16x8;
typedef __attribute__((ext_vector_type(4))) float f32x4;

__device__ __forceinline__ unsigned short f32_to_bf16(float f) {
    unsigned int u = __float_as_uint(f);
    return (unsigned short)((u + 0x7fffu + ((u >> 16) & 1u)) >> 16);
}
__device__ __forceinline__ float bf16lo(unsigned int v) { return __uint_as_float(v << 16); }
__device__ __forceinline__ float bf16hi(unsigned int v) { return __uint_as_float(v & 0xffff0000u); }

// ---------------------------------------------------------------------------
// Pack W helper
// ---------------------------------------------------------------------------
template <int NOUT>
__device__ void pack_w_body(int idx, const float* __restrict__ Wself,
                            const float* __restrict__ Wneigh,
                            unsigned short* __restrict__ Bp) {
    constexpr int NT = NOUT / 16;
    constexpr int NO = NOUT / 2;
    if (idx >= 4 * NT * 64) return;
    const int lane = idx & 63;
    const int tc = idx >> 6;
    const int c = tc % NT;
    const int t = tc / NT;
    const int n = c * 16 + (lane & 15);
    const int k0 = t * 32 + (lane >> 4) * 8;
    const float* W = (n < NO) ? Wself : Wneigh;
    const int nn = (n < NO) ? n : n - NO;
    ushort4 lo, hi;
    lo.x = f32_to_bf16(W[(k0 + 0) * NO + nn]);
    lo.y = f32_to_bf16(W[(k0 + 1) * NO + nn]);
    lo.z = f32_to_bf16(W[(k0 + 2) * NO + nn]);
    lo.w = f32_to_bf16(W[(k0 + 3) * NO + nn]);
    hi.x = f32_to_bf16(W[(k0 + 4) * NO + nn]);
    hi.y = f32_to_bf16(W[(k0 + 5) * NO + nn]);
    hi.z = f32_to_bf16(W[(k0 + 6) * NO + nn]);
    hi.w = f32_to_bf16(W[(k0 + 7) * NO + nn]);
    ((ushort4*)&Bp[(size_t)idx * 8])[0] = lo;
    ((ushort4*)&Bp[(size_t)idx * 8])[1] = hi;
}

// ---------------------------------------------------------------------------
// A0: per-block LDS bucket histogram
// ---------------------------------------------------------------------------
__device__ void a0_body(int blk, const int* __restrict__ dst, int* __restrict__ bcount) {
    __shared__ int h[NBUCK];
    const int t = threadIdx.x;
    h[t] = 0;
    __syncthreads();
    const int lo = blk * A0_CHUNK;
    const int hi = min(lo + A0_CHUNK, N_EDGES);
    for (int i = lo + t; i < hi; i += 256) {
        atomicAdd(&h[dst[i] / BUCK_NODES], 1);
    }
    __syncthreads();
    if (h[t] > 0) atomicAdd(&bcount[t], h[t]);
}

// ---------------------------------------------------------------------------
// Fused prep: [cast | bucket hist | pack W1 | pack W2]
// ---------------------------------------------------------------------------
__global__ __launch_bounds__(256) void prep_kernel(
        const float* __restrict__ x, unsigned short* __restrict__ xb,
        const int* __restrict__ dst, int* __restrict__ bcount,
        const float* __restrict__ Ws1, const float* __restrict__ Wn1,
        unsigned short* __restrict__ Bp1,
        const float* __restrict__ Ws2, const float* __restrict__ Wn2,
        unsigned short* __restrict__ Bp2) {
    const int b = blockIdx.x;
    const int t = threadIdx.x;
    if (b < CAST_BLK) {
        int i = b * 256 + t;
        float4 v = ((const float4*)x)[i];
        ushort4 o;
        o.x = f32_to_bf16(v.x);
        o.y = f32_to_bf16(v.y);
        o.z = f32_to_bf16(v.z);
        o.w = f32_to_bf16(v.w);
        ((ushort4*)xb)[i] = o;
    } else if (b < CAST_BLK + A0_BLK) {
        a0_body(b - CAST_BLK, dst, bcount);
    } else if (b < CAST_BLK + A0_BLK + PACK1_BLK) {
        int idx = (b - CAST_BLK - A0_BLK) * 256 + t;
        pack_w_body<256>(idx, Ws1, Wn1, Bp1);
    } else {
        int idx = (b - CAST_BLK - A0_BLK - PACK1_BLK) * 256 + t;
        pack_w_body<128>(idx, Ws2, Wn2, Bp2);
    }
}

// ---------------------------------------------------------------------------
// Bucket scan
// ---------------------------------------------------------------------------
__global__ __launch_bounds__(256) void bscan_kernel(const int* __restrict__ bcount,
                                                    int* __restrict__ bstart,
                                                    int* __restrict__ bcursor) {
    __shared__ int sc[NBUCK];
    const int t = threadIdx.x;
    const int v = bcount[t];
    sc[t] = v;
    __syncthreads();
    for (int s = 1; s < NBUCK; s <<= 1) {
        int u = (t >= s) ? sc[t - s] : 0;
        __syncthreads();
        sc[t] += u;
        __syncthreads();
    }
    const int excl = sc[t] - v;
    bstart[t] = excl;
    bcursor[t] = excl;
    if (t == NBUCK - 1) bstart[NBUCK] = sc[t];
}

// ---------------------------------------------------------------------------
// A1: bin edges into bucket regions as (dst_local<<16 | src), 2048-edge chunks
// ---------------------------------------------------------------------------
__device__ void a1_body(int blk, const int* __restrict__ src, const int* __restrict__ dst,
                        int* __restrict__ bcursor, unsigned int* __restrict__ binned) {
    __shared__ int h[NBUCK];
    __shared__ int base[NBUCK];
    const int t = threadIdx.x;
    h[t] = 0;
    __syncthreads();
    const int lo = blk * BIN_CHUNK;
    const int hi = min(lo + BIN_CHUNK, N_EDGES);
    for (int i = lo + t; i < hi; i += 256) {
        atomicAdd(&h[dst[i] / BUCK_NODES], 1);
    }
    __syncthreads();
    if (h[t] > 0) base[t] = atomicAdd(&bcursor[t], h[t]);
    h[t] = 0;
    __syncthreads();
    for (int i = lo + t; i < hi; i += 256) {
        const int d = dst[i];
        const int b = d / BUCK_NODES;
        const int r = atomicAdd(&h[b], 1);
        binned[base[b] + r] = ((unsigned int)(d - b * BUCK_NODES) << 16) | (unsigned int)src[i];
    }
}

// ---------------------------------------------------------------------------
// MFMA dual GEMM body (verified R5-R7)
// ---------------------------------------------------------------------------
template <int NOUT>
__device__ void gemm_mfma_body(int gblk,
                               const unsigned short* __restrict__ xb,
                               const unsigned short* __restrict__ Bp,
                               const float* __restrict__ bias,
                               float* __restrict__ s,
                               unsigned short* __restrict__ p) {
    constexpr int NT = NOUT / 16;
    constexpr int NO = NOUT / 2;
    constexpr int NSUB = NT / 4;

    const int tid = threadIdx.x;
    const int wave = tid >> 6;
    const int lane = tid & 63;
    const int mcol = lane & 15;
    const int kgrp = lane >> 4;

    const int mbase = gblk * 32;
    int r0 = mbase + mcol;       if (r0 >= N_NODES) r0 = N_NODES - 1;
    int r1 = mbase + 16 + mcol;  if (r1 >= N_NODES) r1 = N_NODES - 1;

    f32x4 acc[2][NSUB];
#pragma unroll
    for (int mt = 0; mt < 2; ++mt)
#pragma unroll
        for (int c = 0; c < NSUB; ++c)
            acc[mt][c] = (f32x4){0.f, 0.f, 0.f, 0.f};

#pragma unroll
    for (int t = 0; t < 4; ++t) {
        bf16x8 a0 = *(const bf16x8*)&xb[(size_t)r0 * 128 + t * 32 + kgrp * 8];
        bf16x8 a1 = *(const bf16x8*)&xb[(size_t)r1 * 128 + t * 32 + kgrp * 8];
#pragma unroll
        for (int c = 0; c < NSUB; ++c) {
            const int ct = wave * NSUB + c;
            bf16x8 bfrag = *(const bf16x8*)&Bp[((size_t)(t * NT + ct) * 64 + lane) * 8];
            acc[0][c] = __builtin_amdgcn_mfma_f32_16x16x32_bf16(a0, bfrag, acc[0][c], 0, 0, 0);
            acc[1][c] = __builtin_amdgcn_mfma_f32_16x16x32_bf16(a1, bfrag, acc[1][c], 0, 0, 0);
        }
    }

    float bv[NSUB];
    int ncols[NSUB];
#pragma unroll
    for (int c = 0; c < NSUB; ++c) {
        ncols[c] = (wave * NSUB + c) * 16 + mcol;
        bv[c] = (ncols[c] < NO) ? bias[ncols[c]] : 0.f;
    }

#pragma unroll
    for (int mt = 0; mt < 2; ++mt) {
#pragma unroll
        for (int c = 0; c < NSUB; ++c) {
            const int ncol = ncols[c];
#pragma unroll
            for (int r = 0; r < 4; ++r) {
                const int node = mbase + mt * 16 + kgrp * 4 + r;
                if (node >= N_NODES) continue;
                const float v = acc[mt][c][r];
                if (ncol < NO) {
                    s[(size_t)node * NO + ncol] = v + bv[c];
                } else {
                    p[(size_t)node * NO + (ncol - NO)] = f32_to_bf16(v);
                }
            }
        }
    }
}

__global__ __launch_bounds__(256) void bin_gemm1_kernel(
        const int* __restrict__ src, const int* __restrict__ dst,
        int* __restrict__ bcursor, unsigned int* __restrict__ binned,
        const unsigned short* __restrict__ xb,
        const unsigned short* __restrict__ Bp1,
        const float* __restrict__ b1,
        float* __restrict__ s1, unsigned short* __restrict__ p1) {
    const int b = blockIdx.x;
    if (b < BIN_BLK) {
        a1_body(b, src, dst, bcursor, binned);
    } else {
        gemm_mfma_body<256>(b - BIN_BLK, xb, Bp1, b1, s1, p1);
    }
}

// ---------------------------------------------------------------------------
// Pass B: per-bucket counting sort -> csr16 + offsets (verified R7)
// ---------------------------------------------------------------------------
__global__ __launch_bounds__(256) void bucket_build_kernel(
        const unsigned int* __restrict__ binned,
        const int* __restrict__ bstart,
        int* __restrict__ offsets,
        unsigned short* __restrict__ csr16) {
    __shared__ int cnt[NBUCK];
    __shared__ int pre[NBUCK];
    const int b = blockIdx.x;
    const int t = threadIdx.x;
    const int n0 = b * BUCK_NODES;
    const int nn = min(N_NODES - n0, BUCK_NODES);
    const int e0 = bstart[b];
    const int e1 = bstart[b + 1];

    cnt[t] = 0;
    __syncthreads();
    for (int i = e0 + t; i < e1; i += 256) {
        atomicAdd(&cnt[binned[i] >> 16], 1);
    }
    __syncthreads();
    int v = cnt[t];
    pre[t] = v;
    __syncthreads();
    for (int s = 1; s < NBUCK; s <<= 1) {
        int u = (t >= s) ? pre[t - s] : 0;
        __syncthreads();
        pre[t] += u;
        __syncthreads();
    }
    const int excl = pre[t] - v;
    if (t < nn) offsets[n0 + t] = e0 + excl;
    if (b == 0 && t == 0) offsets[N_NODES] = N_EDGES;
    __syncthreads();
    pre[t] = excl;
    cnt[t] = 0;
    __syncthreads();
    for (int i = e0 + t; i < e1; i += 256) {
        const unsigned int u = binned[i];
        const int dl = (int)(u >> 16);
        const int r = atomicAdd(&cnt[dl], 1);
        csr16[e0 + pre[dl] + r] = (unsigned short)(u & 0xffffu);
    }
}

__global__ __launch_bounds__(256) void gemm2_kernel(
        const unsigned short* __restrict__ h1b,
        const unsigned short* __restrict__ Bp2,
        const float* __restrict__ b2,
        float* __restrict__ s2, unsigned short* __restrict__ p2) {
    gemm_mfma_body<128>(blockIdx.x, h1b, Bp2, b2, s2, p2);
}

// ---------------------------------------------------------------------------
// Aggregate, F=128: wave/node, quarter-wave streams, uint4 (16B) loads, 4 deep.
// Lane = (q, l): q=lane>>4 stream, l=lane&15 covers feats [l*8, l*8+8).
// h1b = relu(s + mean gather(p))  (bf16 out)
// ---------------------------------------------------------------------------
__global__ __launch_bounds__(256) void agg_relu_128_kernel(
        const float* __restrict__ s,
        const unsigned short* __restrict__ p,
        const int* __restrict__ offsets,
        const unsigned short* __restrict__ csr16,
        unsigned short* __restrict__ h1b) {
    const int wave = threadIdx.x >> 6;
    const int lane = threadIdx.x & 63;
    const int q = lane >> 4;
    const int l = lane & 15;
    const int node = blockIdx.x * 4 + wave;
    if (node >= N_NODES) return;

    const int off0 = offsets[node];
    const int off1 = offsets[node + 1];
    const uint4* pp = (const uint4*)p;   // row stride 16 uint4 (256B)

    float a0 = 0.f, a1 = 0.f, a2 = 0.f, a3 = 0.f;
    float a4 = 0.f, a5 = 0.f, a6 = 0.f, a7 = 0.f;
    int i = off0 + q;
    for (; i + 12 < off1; i += 16) {   // 4 neighbors per stream per iter
        uint4 v0 = pp[(size_t)csr16[i + 0] * 16 + l];
        uint4 v1 = pp[(size_t)csr16[i + 4] * 16 + l];
        uint4 v2 = pp[(size_t)csr16[i + 8] * 16 + l];
        uint4 v3 = pp[(size_t)csr16[i + 12] * 16 + l];
        a0 += bf16lo(v0.x) + bf16lo(v1.x) + bf16lo(v2.x) + bf16lo(v3.x);
        a1 += bf16hi(v0.x) + bf16hi(v1.x) + bf16hi(v2.x) + bf16hi(v3.x);
        a2 += bf16lo(v0.y) + bf16lo(v1.y) + bf16lo(v2.y) + bf16lo(v3.y);
        a3 += bf16hi(v0.y) + bf16hi(v1.y) + bf16hi(v2.y) + bf16hi(v3.y);
        a4 += bf16lo(v0.z) + bf16lo(v1.z) + bf16lo(v2.z) + bf16lo(v3.z);
        a5 += bf16hi(v0.z) + bf16hi(v1.z) + bf16hi(v2.z) + bf16hi(v3.z);
        a6 += bf16lo(v0.w) + bf16lo(v1.w) + bf16lo(v2.w) + bf16lo(v3.w);
        a7 += bf16hi(v0.w) + bf16hi(v1.w) + bf16hi(v2.w) + bf16hi(v3.w);
    }
    for (; i < off1; i += 4) {
        uint4 v = pp[(size_t)csr16[i] * 16 + l];
        a0 += bf16lo(v.x); a1 += bf16hi(v.x);
        a2 += bf16lo(v.y); a3 += bf16hi(v.y);
        a4 += bf16lo(v.z); a5 += bf16hi(v.z);
        a6 += bf16lo(v.w); a7 += bf16hi(v.w);
    }
    a0 += __shfl_xor(a0, 16); a0 += __shfl_xor(a0, 32);
    a1 += __shfl_xor(a1, 16); a1 += __shfl_xor(a1, 32);
    a2 += __shfl_xor(a2, 16); a2 += __shfl_xor(a2, 32);
    a3 += __shfl_xor(a3, 16); a3 += __shfl_xor(a3, 32);
    a4 += __shfl_xor(a4, 16); a4 += __shfl_xor(a4, 32);
    a5 += __shfl_xor(a5, 16); a5 += __shfl_xor(a5, 32);
    a6 += __shfl_xor(a6, 16); a6 += __shfl_xor(a6, 32);
    a7 += __shfl_xor(a7, 16); a7 += __shfl_xor(a7, 32);

    if (q == 0) {
        const float invdeg = 1.0f / fmaxf((float)(off1 - off0), 1.0f);
        float4 s0 = ((const float4*)s)[(size_t)node * 32 + l * 2];
        float4 s1 = ((const float4*)s)[(size_t)node * 32 + l * 2 + 1];
        ushort4 o0, o1;
        o0.x = f32_to_bf16(fmaxf(s0.x + a0 * invdeg, 0.f));
        o0.y = f32_to_bf16(fmaxf(s0.y + a1 * invdeg, 0.f));
        o0.z = f32_to_bf16(fmaxf(s0.z + a2 * invdeg, 0.f));
        o0.w = f32_to_bf16(fmaxf(s0.w + a3 * invdeg, 0.f));
        o1.x = f32_to_bf16(fmaxf(s1.x + a4 * invdeg, 0.f));
        o1.y = f32_to_bf16(fmaxf(s1.y + a5 * invdeg, 0.f));
        o1.z = f32_to_bf16(fmaxf(s1.z + a6 * invdeg, 0.f));
        o1.w = f32_to_bf16(fmaxf(s1.w + a7 * invdeg, 0.f));
        ((ushort4*)h1b)[(size_t)node * 32 + l * 2] = o0;
        ((ushort4*)h1b)[(size_t)node * 32 + l * 2 + 1] = o1;
    }
}

// ---------------------------------------------------------------------------
// Aggregate, F=64: wave/node, 8-lane streams, uint4 loads, 4 deep.
// Lane = (st, l): st=lane>>3 stream, l=lane&7 covers feats [l*8, l*8+8).
// out += mean gather(p)  (fp32 in place)
// ---------------------------------------------------------------------------
__global__ __launch_bounds__(256) void agg_64_kernel(
        const unsigned short* __restrict__ p,
        const int* __restrict__ offsets,
        const unsigned short* __restrict__ csr16,
        float* __restrict__ out) {
    const int wave = threadIdx.x >> 6;
    const int lane = threadIdx.x & 63;
    const int st = lane >> 3;
    const int l = lane & 7;
    const int node = blockIdx.x * 4 + wave;
    if (node >= N_NODES) return;

    const int off0 = offsets[node];
    const int off1 = offsets[node + 1];
    const uint4* pp = (const uint4*)p;   // row stride 8 uint4 (128B)

    float a0 = 0.f, a1 = 0.f, a2 = 0.f, a3 = 0.f;
    float a4 = 0.f, a5 = 0.f, a6 = 0.f, a7 = 0.f;
    int i = off0 + st;
    for (; i + 24 < off1; i += 32) {   // 4 neighbors per stream per iter
        uint4 v0 = pp[(size_t)csr16[i + 0] * 8 + l];
        uint4 v1 = pp[(size_t)csr16[i + 8] * 8 + l];
        uint4 v2 = pp[(size_t)csr16[i + 16] * 8 + l];
        uint4 v3 = pp[(size_t)csr16[i + 24] * 8 + l];
        a0 += bf16lo(v0.x) + bf16lo(v1.x) + bf16lo(v2.x) + bf16lo(v3.x);
        a1 += bf16hi(v0.x) + bf16hi(v1.x) + bf16hi(v2.x) + bf16hi(v3.x);
        a2 += bf16lo(v0.y) + bf16lo(v1.y) + bf16lo(v2.y) + bf16lo(v3.y);
        a3 += bf16hi(v0.y) + bf16hi(v1.y) + bf16hi(v2.y) + bf16hi(v3.y);
        a4 += bf16lo(v0.z) + bf16lo(v1.z) + bf16lo(v2.z) + bf16lo(v3.z);
        a5 += bf16hi(v0.z) + bf16hi(v1.z) + bf16hi(v2.z) + bf16hi(v3.z);
        a6 += bf16lo(v0.w) + bf16lo(v1.w) + bf16lo(v2.w) + bf16lo(v3.w);
        a7 += bf16hi(v0.w) + bf16hi(v1.w) + bf16hi(v2.w) + bf16hi(v3.w);
    }
    for (; i < off1; i += 8) {
        uint4 v = pp[(size_t)csr16[i] * 8 + l];
        a0 += bf16lo(v.x); a1 += bf16hi(v.x);
        a2 += bf16lo(v.y); a3 += bf16hi(v.y);
        a4 += bf16lo(v.z); a5 += bf16hi(v.z);
        a6 += bf16lo(v.w); a7 += bf16hi(v.w);
    }
    a0 += __shfl_xor(a0, 8); a0 += __shfl_xor(a0, 16); a0 += __shfl_xor(a0, 32);
    a1 += __shfl_xor(a1, 8); a1 += __shfl_xor(a1, 16); a1 += __shfl_xor(a1, 32);
    a2 += __shfl_xor(a2, 8); a2 += __shfl_xor(a2, 16); a2 += __shfl_xor(a2, 32);
    a3 += __shfl_xor(a3, 8); a3 += __shfl_xor(a3, 16); a3 += __shfl_xor(a3, 32);
    a4 += __shfl_xor(a4, 8); a4 += __shfl_xor(a4, 16); a4 += __shfl_xor(a4, 32);
    a5 += __shfl_xor(a5, 8); a5 += __shfl_xor(a5, 16); a5 += __shfl_xor(a5, 32);
    a6 += __shfl_xor(a6, 8); a6 += __shfl_xor(a6, 16); a6 += __shfl_xor(a6, 32);
    a7 += __shfl_xor(a7, 8); a7 += __shfl_xor(a7, 16); a7 += __shfl_xor(a7, 32);

    if (st == 0) {
        const float invdeg = 1.0f / fmaxf((float)(off1 - off0), 1.0f);
        float4 s0 = ((float4*)out)[(size_t)node * 16 + l * 2];
        float4 s1 = ((float4*)out)[(size_t)node * 16 + l * 2 + 1];
        s0.x += a0 * invdeg; s0.y += a1 * invdeg;
        s0.z += a2 * invdeg; s0.w += a3 * invdeg;
        s1.x += a4 * invdeg; s1.y += a5 * invdeg;
        s1.z += a6 * invdeg; s1.w += a7 * invdeg;
        ((float4*)out)[(size_t)node * 16 + l * 2] = s0;
        ((float4*)out)[(size_t)node * 16 + l * 2 + 1] = s1;
    }
}

extern "C" void kernel_launch(void* const* d_in, const int* in_sizes, int n_in,
                              void* d_out, int out_size, void* d_ws, size_t ws_size,
                              hipStream_t stream) {
    const float* x        = (const float*)d_in[0];
    const float* W_self1  = (const float*)d_in[1];
    const float* W_neigh1 = (const float*)d_in[2];
    const float* b1       = (const float*)d_in[3];
    const float* W_self2  = (const float*)d_in[4];
    const float* W_neigh2 = (const float*)d_in[5];
    const float* b2       = (const float*)d_in[6];
    const int*   src      = (const int*)d_in[7];
    const int*   dst      = (const int*)d_in[8];
    float* out = (float*)d_out;

    int* bcount  = (int*)d_ws;                        // 256
    int* bstart  = bcount + 256;                      // 288 (uses 257)
    int* bcursor = bstart + 288;                      // 256
    int* offsets = bcursor + 256;                     // 50048
    unsigned int* binned = (unsigned int*)(offsets + 50048);              // 800000
    unsigned short* csr16 = (unsigned short*)(binned + 800000);           // 800000 ushort
    unsigned short* Bp1 = csr16 + 800000;                                  // 32768 bf16
    unsigned short* Bp2 = Bp1 + 32768;                                     // 16384 bf16
    unsigned short* xb  = Bp2 + 16384;                                     // 6.4M bf16 (-> h1b)
    unsigned short* h1b = xb;
    float* s1 = (float*)(xb + (size_t)N_NODES * 128);                      // 6.4M fp32
    unsigned short* p1 = (unsigned short*)(s1 + (size_t)N_NODES * 128);    // 6.4M bf16 (-> p2)
    unsigned short* p2 = p1;

    hipMemsetAsync(bcount, 0, 256 * sizeof(int), stream);
    prep_kernel<<<PREP_BLK, 256, 0, stream>>>(x, xb, dst, bcount,
                                              W_self1, W_neigh1, Bp1,
                                              W_self2, W_neigh2, Bp2);
    bscan_kernel<<<1, 256, 0, stream>>>(bcount, bstart, bcursor);
    bin_gemm1_kernel<<<BG_BLK, 256, 0, stream>>>(src, dst, bcursor, binned,
                                                 xb, Bp1, b1, s1, p1);
    bucket_build_kernel<<<NBUCK, 256, 0, stream>>>(binned, bstart, offsets, csr16);
    agg_relu_128_kernel<<<(N_NODES + 3) / 4, 256, 0, stream>>>(s1, p1, offsets, csr16, h1b);
    gemm2_kernel<<<(N_NODES + 31) / 32, 256, 0, stream>>>(h1b, Bp2, b2, out, p2);
    agg_64_kernel<<<(N_NODES + 3) / 4, 256, 0, stream>>>(p2, offsets, csr16, out);
}

// Round 9
// 207.757 us; speedup vs baseline: 5.3182x; 1.0095x over previous
//
#include <hip/hip_runtime.h>
#include <hip/hip_fp16.h>

#define N_NODES 50000
#define N_EDGES 800000
#define N_FEAT 128
#define N_HIDDEN 128
#define N_CLASSES 64

#define NBUCK 256
#define BUCK_NODES 196        // ceil(50000/256)
#define BIN_CHUNK 2048
#define BIN_BLK ((N_EDGES + BIN_CHUNK - 1) / BIN_CHUNK)   // 391

#define CAST_BLK 6250
#define PACK1_BLK 16
#define PACK2_BLK 8
#define PREP_BLK (CAST_BLK + BIN_BLK + PACK1_BLK + PACK2_BLK)
#define GEMM1_BLK ((N_NODES + 31) / 32)   // 1563
#define BG_BLK (BIN_BLK + GEMM1_BLK)

typedef __attribute__((ext_vector_type(8))) short bf16x8;
typedef __attribute__((ext_vector_type(4))) float f32x4;
typedef __attribute__((ext_vector_type(2))) float f32x2;

__device__ __forceinline__ unsigned short f32_to_bf16(float f) {
    unsigned int u = __float_as_uint(f);
    return (unsigned short)((u + 0x7fffu + ((u >> 16) & 1u)) >> 16);
}
__device__ __forceinline__ float bf16lo(unsigned int v) { return __uint_as_float(v << 16); }
__device__ __forceinline__ float bf16hi(unsigned int v) { return __uint_as_float(v & 0xffff0000u); }

// ---------------- fp8 helpers: HW e4m3 path, e5m2-shift fallback ----------
#if defined(__has_builtin)
#if __has_builtin(__builtin_amdgcn_cvt_pk_f32_fp8) && __has_builtin(__builtin_amdgcn_cvt_pk_fp8_f32)
#define FP8_HW 1
#endif
#endif

__device__ __forceinline__ unsigned char f32_to_fp8(float f) {
#ifdef FP8_HW
    return (unsigned char)(__builtin_amdgcn_cvt_pk_fp8_f32(f, f, 0, false) & 0xff);
#else
    unsigned short hb = __half_as_ushort(__float2half(f));
    return (unsigned char)((hb + 0x7fu + ((hb >> 8) & 1u)) >> 8);
#endif
}

// decode 4 fp8 (one uint) -> 4 floats
__device__ __forceinline__ void fp8x4_to_f32(unsigned int u, float* o) {
#ifdef FP8_HW
    f32x2 lo = __builtin_amdgcn_cvt_pk_f32_fp8(u, false);
    f32x2 hi = __builtin_amdgcn_cvt_pk_f32_fp8(u, true);
    o[0] = lo.x; o[1] = lo.y; o[2] = hi.x; o[3] = hi.y;
#else
    o[0] = __half2float(__ushort_as_half((unsigned short)((u & 0xffu) << 8)));
    o[1] = __half2float(__ushort_as_half((unsigned short)(((u >> 8) & 0xffu) << 8)));
    o[2] = __half2float(__ushort_as_half((unsigned short)(((u >> 16) & 0xffu) << 8)));
    o[3] = __half2float(__ushort_as_half((unsigned short)(((u >> 24) & 0xffu) << 8)));
#endif
}

// ---------------------------------------------------------------------------
// Pack W helper
// ---------------------------------------------------------------------------
template <int NOUT>
__device__ void pack_w_body(int idx, const float* __restrict__ Wself,
                            const float* __restrict__ Wneigh,
                            unsigned short* __restrict__ Bp) {
    constexpr int NT = NOUT / 16;
    constexpr int NO = NOUT / 2;
    if (idx >= 4 * NT * 64) return;
    const int lane = idx & 63;
    const int tc = idx >> 6;
    const int c = tc % NT;
    const int t = tc / NT;
    const int n = c * 16 + (lane & 15);
    const int k0 = t * 32 + (lane >> 4) * 8;
    const float* W = (n < NO) ? Wself : Wneigh;
    const int nn = (n < NO) ? n : n - NO;
    ushort4 lo, hi;
    lo.x = f32_to_bf16(W[(k0 + 0) * NO + nn]);
    lo.y = f32_to_bf16(W[(k0 + 1) * NO + nn]);
    lo.z = f32_to_bf16(W[(k0 + 2) * NO + nn]);
    lo.w = f32_to_bf16(W[(k0 + 3) * NO + nn]);
    hi.x = f32_to_bf16(W[(k0 + 4) * NO + nn]);
    hi.y = f32_to_bf16(W[(k0 + 5) * NO + nn]);
    hi.z = f32_to_bf16(W[(k0 + 6) * NO + nn]);
    hi.w = f32_to_bf16(W[(k0 + 7) * NO + nn]);
    ((ushort4*)&Bp[(size_t)idx * 8])[0] = lo;
    ((ushort4*)&Bp[(size_t)idx * 8])[1] = hi;
}

// ---------------------------------------------------------------------------
// A0: per-chunk LDS bucket histogram -> hists[chunk][256]  (plain stores)
// ---------------------------------------------------------------------------
__device__ void a0_body(int blk, const int* __restrict__ dst, int* __restrict__ hists) {
    __shared__ int h[NBUCK];
    const int t = threadIdx.x;
    h[t] = 0;
    __syncthreads();
    const int lo = blk * BIN_CHUNK;
    const int hi = min(lo + BIN_CHUNK, N_EDGES);
    for (int i = lo + t; i < hi; i += 256) {
        atomicAdd(&h[dst[i] / BUCK_NODES], 1);
    }
    __syncthreads();
    hists[blk * NBUCK + t] = h[t];
}

// ---------------------------------------------------------------------------
// Fused prep: [cast | bucket hists | pack W1 | pack W2]
// ---------------------------------------------------------------------------
__global__ __launch_bounds__(256) void prep_kernel(
        const float* __restrict__ x, unsigned short* __restrict__ xb,
        const int* __restrict__ dst, int* __restrict__ hists,
        const float* __restrict__ Ws1, const float* __restrict__ Wn1,
        unsigned short* __restrict__ Bp1,
        const float* __restrict__ Ws2, const float* __restrict__ Wn2,
        unsigned short* __restrict__ Bp2) {
    const int b = blockIdx.x;
    const int t = threadIdx.x;
    if (b < CAST_BLK) {
        int i = b * 256 + t;
        float4 v = ((const float4*)x)[i];
        ushort4 o;
        o.x = f32_to_bf16(v.x);
        o.y = f32_to_bf16(v.y);
        o.z = f32_to_bf16(v.z);
        o.w = f32_to_bf16(v.w);
        ((ushort4*)xb)[i] = o;
    } else if (b < CAST_BLK + BIN_BLK) {
        a0_body(b - CAST_BLK, dst, hists);
    } else if (b < CAST_BLK + BIN_BLK + PACK1_BLK) {
        int idx = (b - CAST_BLK - BIN_BLK) * 256 + t;
        pack_w_body<256>(idx, Ws1, Wn1, Bp1);
    } else {
        int idx = (b - CAST_BLK - BIN_BLK - PACK1_BLK) * 256 + t;
        pack_w_body<128>(idx, Ws2, Wn2, Bp2);
    }
}

// ---------------------------------------------------------------------------
// Bucket scan: reduce hists columns + exclusive scan -> bstart[257], bcursor
// ---------------------------------------------------------------------------
__global__ __launch_bounds__(256) void bscan_kernel(const int* __restrict__ hists,
                                                    int* __restrict__ bstart,
                                                    int* __restrict__ bcursor) {
    __shared__ int sc[NBUCK];
    const int t = threadIdx.x;
    int v = 0;
#pragma unroll 8
    for (int c = 0; c < BIN_BLK; ++c) v += hists[c * NBUCK + t];
    sc[t] = v;
    __syncthreads();
    for (int s = 1; s < NBUCK; s <<= 1) {
        int u = (t >= s) ? sc[t - s] : 0;
        __syncthreads();
        sc[t] += u;
        __syncthreads();
    }
    const int excl = sc[t] - v;
    bstart[t] = excl;
    bcursor[t] = excl;
    if (t == NBUCK - 1) bstart[NBUCK] = sc[t];
}

// ---------------------------------------------------------------------------
// A1: bin edges into bucket regions as (dst_local<<16 | src).
// Reads its per-chunk counts from hists (no LDS phase-1 pass).
// ---------------------------------------------------------------------------
__device__ void a1_body(int blk, const int* __restrict__ src, const int* __restrict__ dst,
                        const int* __restrict__ hists,
                        int* __restrict__ bcursor, unsigned int* __restrict__ binned) {
    __shared__ int base[NBUCK];
    __shared__ int cnt[NBUCK];
    const int t = threadIdx.x;
    const int h = hists[blk * NBUCK + t];
    base[t] = atomicAdd(&bcursor[t], h);
    cnt[t] = 0;
    __syncthreads();
    const int lo = blk * BIN_CHUNK;
    const int hi = min(lo + BIN_CHUNK, N_EDGES);
    for (int i = lo + t; i < hi; i += 256) {
        const int d = dst[i];
        const int b = d / BUCK_NODES;
        const int r = atomicAdd(&cnt[b], 1);
        binned[base[b] + r] = ((unsigned int)(d - b * BUCK_NODES) << 16) | (unsigned int)src[i];
    }
}

// ---------------------------------------------------------------------------
// MFMA dual GEMM body (verified R5-R8); PFP8 selects fp8 vs bf16 p-output
// ---------------------------------------------------------------------------
template <int NOUT, bool PFP8>
__device__ void gemm_mfma_body(int gblk,
                               const unsigned short* __restrict__ xb,
                               const unsigned short* __restrict__ Bp,
                               const float* __restrict__ bias,
                               float* __restrict__ s,
                               unsigned char* __restrict__ p8,
                               unsigned short* __restrict__ p16) {
    constexpr int NT = NOUT / 16;
    constexpr int NO = NOUT / 2;
    constexpr int NSUB = NT / 4;

    const int tid = threadIdx.x;
    const int wave = tid >> 6;
    const int lane = tid & 63;
    const int mcol = lane & 15;
    const int kgrp = lane >> 4;

    const int mbase = gblk * 32;
    int r0 = mbase + mcol;       if (r0 >= N_NODES) r0 = N_NODES - 1;
    int r1 = mbase + 16 + mcol;  if (r1 >= N_NODES) r1 = N_NODES - 1;

    f32x4 acc[2][NSUB];
#pragma unroll
    for (int mt = 0; mt < 2; ++mt)
#pragma unroll
        for (int c = 0; c < NSUB; ++c)
            acc[mt][c] = (f32x4){0.f, 0.f, 0.f, 0.f};

#pragma unroll
    for (int t = 0; t < 4; ++t) {
        bf16x8 a0 = *(const bf16x8*)&xb[(size_t)r0 * 128 + t * 32 + kgrp * 8];
        bf16x8 a1 = *(const bf16x8*)&xb[(size_t)r1 * 128 + t * 32 + kgrp * 8];
#pragma unroll
        for (int c = 0; c < NSUB; ++c) {
            const int ct = wave * NSUB + c;
            bf16x8 bfrag = *(const bf16x8*)&Bp[((size_t)(t * NT + ct) * 64 + lane) * 8];
            acc[0][c] = __builtin_amdgcn_mfma_f32_16x16x32_bf16(a0, bfrag, acc[0][c], 0, 0, 0);
            acc[1][c] = __builtin_amdgcn_mfma_f32_16x16x32_bf16(a1, bfrag, acc[1][c], 0, 0, 0);
        }
    }

    float bv[NSUB];
    int ncols[NSUB];
#pragma unroll
    for (int c = 0; c < NSUB; ++c) {
        ncols[c] = (wave * NSUB + c) * 16 + mcol;
        bv[c] = (ncols[c] < NO) ? bias[ncols[c]] : 0.f;
    }

#pragma unroll
    for (int mt = 0; mt < 2; ++mt) {
#pragma unroll
        for (int c = 0; c < NSUB; ++c) {
            const int ncol = ncols[c];
#pragma unroll
            for (int r = 0; r < 4; ++r) {
                const int node = mbase + mt * 16 + kgrp * 4 + r;
                if (node >= N_NODES) continue;
                const float v = acc[mt][c][r];
                if (ncol < NO) {
                    s[(size_t)node * NO + ncol] = v + bv[c];
                } else if (PFP8) {
                    p8[(size_t)node * NO + (ncol - NO)] = f32_to_fp8(v);
                } else {
                    p16[(size_t)node * NO + (ncol - NO)] = f32_to_bf16(v);
                }
            }
        }
    }
}

__global__ __launch_bounds__(256) void bin_gemm1_kernel(
        const int* __restrict__ src, const int* __restrict__ dst,
        const int* __restrict__ hists,
        int* __restrict__ bcursor, unsigned int* __restrict__ binned,
        const unsigned short* __restrict__ xb,
        const unsigned short* __restrict__ Bp1,
        const float* __restrict__ b1,
        float* __restrict__ s1, unsigned char* __restrict__ p1) {
    const int b = blockIdx.x;
    if (b < BIN_BLK) {
        a1_body(b, src, dst, hists, bcursor, binned);
    } else {
        gemm_mfma_body<256, true>(b - BIN_BLK, xb, Bp1, b1, s1, p1, nullptr);
    }
}

// ---------------------------------------------------------------------------
// Pass B: per-bucket counting sort -> csr16 + offsets (verified R7/R8)
// ---------------------------------------------------------------------------
__global__ __launch_bounds__(256) void bucket_build_kernel(
        const unsigned int* __restrict__ binned,
        const int* __restrict__ bstart,
        int* __restrict__ offsets,
        unsigned short* __restrict__ csr16) {
    __shared__ int cnt[NBUCK];
    __shared__ int pre[NBUCK];
    const int b = blockIdx.x;
    const int t = threadIdx.x;
    const int n0 = b * BUCK_NODES;
    const int nn = min(N_NODES - n0, BUCK_NODES);
    const int e0 = bstart[b];
    const int e1 = bstart[b + 1];

    cnt[t] = 0;
    __syncthreads();
    for (int i = e0 + t; i < e1; i += 256) {
        atomicAdd(&cnt[binned[i] >> 16], 1);
    }
    __syncthreads();
    int v = cnt[t];
    pre[t] = v;
    __syncthreads();
    for (int s = 1; s < NBUCK; s <<= 1) {
        int u = (t >= s) ? pre[t - s] : 0;
        __syncthreads();
        pre[t] += u;
        __syncthreads();
    }
    const int excl = pre[t] - v;
    if (t < nn) offsets[n0 + t] = e0 + excl;
    if (b == 0 && t == 0) offsets[N_NODES] = N_EDGES;
    __syncthreads();
    pre[t] = excl;
    cnt[t] = 0;
    __syncthreads();
    for (int i = e0 + t; i < e1; i += 256) {
        const unsigned int u = binned[i];
        const int dl = (int)(u >> 16);
        const int r = atomicAdd(&cnt[dl], 1);
        csr16[e0 + pre[dl] + r] = (unsigned short)(u & 0xffffu);
    }
}

__global__ __launch_bounds__(256) void gemm2_kernel(
        const unsigned short* __restrict__ h1b,
        const unsigned short* __restrict__ Bp2,
        const float* __restrict__ b2,
        float* __restrict__ s2, unsigned short* __restrict__ p2) {
    gemm_mfma_body<128, false>(blockIdx.x, h1b, Bp2, b2, s2, nullptr, p2);
}

// ---------------------------------------------------------------------------
// Aggregate, F=128, p in fp8: wave/node, 4 streams (16 lanes), masked batch
// of 8 neighbors/stream (covers deg<=32 in one batch, all loads in flight).
// Lane (q,l): l covers feats [l*8, l*8+8) = uint2 of the fp8 row (128B).
// h1b = relu(s + mean gather(p))  (bf16 out)
// ---------------------------------------------------------------------------
__global__ __launch_bounds__(256) void agg_relu_128_kernel(
        const float* __restrict__ s,
        const unsigned char* __restrict__ p,
        const int* __restrict__ offsets,
        const unsigned short* __restrict__ csr16,
        unsigned short* __restrict__ h1b) {
    const int wave = threadIdx.x >> 6;
    const int lane = threadIdx.x & 63;
    const int q = lane >> 4;
    const int l = lane & 15;
    const int node = blockIdx.x * 4 + wave;
    if (node >= N_NODES) return;

    const int off0 = offsets[node];
    const int off1 = offsets[node + 1];
    const uint2* pp = (const uint2*)p;   // fp8 row = 16 uint2 (128B)

    float a[8];
#pragma unroll
    for (int k = 0; k < 8; ++k) a[k] = 0.f;

    for (int i = off0 + q; i < off1; i += 32) {
        int idx[8];
        float m[8];
        uint2 w[8];
#pragma unroll
        for (int j = 0; j < 8; ++j) {
            const int e = i + 4 * j;
            const int ec = min(e, off1 - 1);
            idx[j] = (int)csr16[ec];
            m[j] = (e < off1) ? 1.f : 0.f;
        }
#pragma unroll
        for (int j = 0; j < 8; ++j) w[j] = pp[(size_t)idx[j] * 16 + l];
#pragma unroll
        for (int j = 0; j < 8; ++j) {
            float d0[4], d1[4];
            fp8x4_to_f32(w[j].x, d0);
            fp8x4_to_f32(w[j].y, d1);
            a[0] += m[j] * d0[0]; a[1] += m[j] * d0[1];
            a[2] += m[j] * d0[2]; a[3] += m[j] * d0[3];
            a[4] += m[j] * d1[0]; a[5] += m[j] * d1[1];
            a[6] += m[j] * d1[2]; a[7] += m[j] * d1[3];
        }
    }
#pragma unroll
    for (int k = 0; k < 8; ++k) {
        a[k] += __shfl_xor(a[k], 16);
        a[k] += __shfl_xor(a[k], 32);
    }

    if (q == 0) {
        const float invdeg = 1.0f / fmaxf((float)(off1 - off0), 1.0f);
        float4 s0 = ((const float4*)s)[(size_t)node * 32 + l * 2];
        float4 s1 = ((const float4*)s)[(size_t)node * 32 + l * 2 + 1];
        ushort4 o0, o1;
        o0.x = f32_to_bf16(fmaxf(s0.x + a[0] * invdeg, 0.f));
        o0.y = f32_to_bf16(fmaxf(s0.y + a[1] * invdeg, 0.f));
        o0.z = f32_to_bf16(fmaxf(s0.z + a[2] * invdeg, 0.f));
        o0.w = f32_to_bf16(fmaxf(s0.w + a[3] * invdeg, 0.f));
        o1.x = f32_to_bf16(fmaxf(s1.x + a[4] * invdeg, 0.f));
        o1.y = f32_to_bf16(fmaxf(s1.y + a[5] * invdeg, 0.f));
        o1.z = f32_to_bf16(fmaxf(s1.z + a[6] * invdeg, 0.f));
        o1.w = f32_to_bf16(fmaxf(s1.w + a[7] * invdeg, 0.f));
        ((ushort4*)h1b)[(size_t)node * 32 + l * 2] = o0;
        ((ushort4*)h1b)[(size_t)node * 32 + l * 2 + 1] = o1;
    }
}

// ---------------------------------------------------------------------------
// Aggregate, F=64, p in bf16: wave/node, 8 streams (8 lanes), masked batch
// of 4 neighbors/stream (covers deg<=32 in one batch).
// out += mean gather(p)  (fp32 in place)
// ---------------------------------------------------------------------------
__global__ __launch_bounds__(256) void agg_64_kernel(
        const unsigned short* __restrict__ p,
        const int* __restrict__ offsets,
        const unsigned short* __restrict__ csr16,
        float* __restrict__ out) {
    const int wave = threadIdx.x >> 6;
    const int lane = threadIdx.x & 63;
    const int st = lane >> 3;
    const int l = lane & 7;
    const int node = blockIdx.x * 4 + wave;
    if (node >= N_NODES) return;

    const int off0 = offsets[node];
    const int off1 = offsets[node + 1];
    const uint4* pp = (const uint4*)p;   // bf16 row = 8 uint4 (128B)

    float a[8];
#pragma unroll
    for (int k = 0; k < 8; ++k) a[k] = 0.f;

    for (int i = off0 + st; i < off1; i += 32) {
        int idx[4];
        float m[4];
        uint4 w[4];
#pragma unroll
        for (int j = 0; j < 4; ++j) {
            const int e = i + 8 * j;
            const int ec = min(e, off1 - 1);
            idx[j] = (int)csr16[ec];
            m[j] = (e < off1) ? 1.f : 0.f;
        }
#pragma unroll
        for (int j = 0; j < 4; ++j) w[j] = pp[(size_t)idx[j] * 8 + l];
#pragma unroll
        for (int j = 0; j < 4; ++j) {
            a[0] += m[j] * bf16lo(w[j].x); a[1] += m[j] * bf16hi(w[j].x);
            a[2] += m[j] * bf16lo(w[j].y); a[3] += m[j] * bf16hi(w[j].y);
            a[4] += m[j] * bf16lo(w[j].z); a[5] += m[j] * bf16hi(w[j].z);
            a[6] += m[j] * bf16lo(w[j].w); a[7] += m[j] * bf16hi(w[j].w);
        }
    }
#pragma unroll
    for (int k = 0; k < 8; ++k) {
        a[k] += __shfl_xor(a[k], 8);
        a[k] += __shfl_xor(a[k], 16);
        a[k] += __shfl_xor(a[k], 32);
    }

    if (st == 0) {
        const float invdeg = 1.0f / fmaxf((float)(off1 - off0), 1.0f);
        float4 s0 = ((float4*)out)[(size_t)node * 16 + l * 2];
        float4 s1 = ((float4*)out)[(size_t)node * 16 + l * 2 + 1];
        s0.x += a[0] * invdeg; s0.y += a[1] * invdeg;
        s0.z += a[2] * invdeg; s0.w += a[3] * invdeg;
        s1.x += a[4] * invdeg; s1.y += a[5] * invdeg;
        s1.z += a[6] * invdeg; s1.w += a[7] * invdeg;
        ((float4*)out)[(size_t)node * 16 + l * 2] = s0;
        ((float4*)out)[(size_t)node * 16 + l * 2 + 1] = s1;
    }
}

extern "C" void kernel_launch(void* const* d_in, const int* in_sizes, int n_in,
                              void* d_out, int out_size, void* d_ws, size_t ws_size,
                              hipStream_t stream) {
    const float* x        = (const float*)d_in[0];
    const float* W_self1  = (const float*)d_in[1];
    const float* W_neigh1 = (const float*)d_in[2];
    const float* b1       = (const float*)d_in[3];
    const float* W_self2  = (const float*)d_in[4];
    const float* W_neigh2 = (const float*)d_in[5];
    const float* b2       = (const float*)d_in[6];
    const int*   src      = (const int*)d_in[7];
    const int*   dst      = (const int*)d_in[8];
    float* out = (float*)d_out;

    // workspace (4B units)
    int* bstart  = (int*)d_ws;                          // 288 (uses 257)
    int* bcursor = bstart + 288;                        // 256
    int* offsets = bcursor + 256;                       // 50048
    int* hists   = offsets + 50048;                     // 391*256 = 100096
    unsigned int* binned = (unsigned int*)(hists + BIN_BLK * NBUCK);      // 800000
    unsigned short* csr16 = (unsigned short*)(binned + 800000);           // 800000 ushort
    unsigned short* Bp1 = csr16 + 800000;                                  // 32768 bf16
    unsigned short* Bp2 = Bp1 + 32768;                                     // 16384 bf16
    unsigned short* xb  = Bp2 + 16384;                                     // 6.4M bf16 (-> h1b)
    unsigned short* h1b = xb;
    float* s1 = (float*)(xb + (size_t)N_NODES * 128);                      // 6.4M fp32
    unsigned char* p1 = (unsigned char*)(s1 + (size_t)N_NODES * 128);      // 6.4M fp8 (-> p2)
    unsigned short* p2 = (unsigned short*)p1;                              // 3.2M bf16 (6.4MB)

    // ---- prep (cast | per-chunk bucket hists | packs) — no memset needed ----
    prep_kernel<<<PREP_BLK, 256, 0, stream>>>(x, xb, dst, hists,
                                              W_self1, W_neigh1, Bp1,
                                              W_self2, W_neigh2, Bp2);
    bscan_kernel<<<1, 256, 0, stream>>>(hists, bstart, bcursor);
    bin_gemm1_kernel<<<BG_BLK, 256, 0, stream>>>(src, dst, hists, bcursor, binned,
                                                 xb, Bp1, b1, s1, p1);
    bucket_build_kernel<<<NBUCK, 256, 0, stream>>>(binned, bstart, offsets, csr16);
    agg_relu_128_kernel<<<(N_NODES + 3) / 4, 256, 0, stream>>>(s1, p1, offsets, csr16, h1b);
    gemm2_kernel<<<(N_NODES + 31) / 32, 256, 0, stream>>>(h1b, Bp2, b2, out, p2);
    agg_64_kernel<<<(N_NODES + 3) / 4, 256, 0, stream>>>(p2, offsets, csr16, out);
}